// Round 3
// baseline (161.035 us; speedup 1.0000x reference)
//
#include <hip/hip_runtime.h>
#include <math.h>

// Problem constants (from reference)
#define MM 129      // mesh points per axis (odd)
#define KP 132      // padded K dim (pad entries zero)
#define NP 512      // points per batch
#define NB 4        // batches

static constexpr double D_PI  = 3.14159265358979323846;
static constexpr double D_L   = 2.0 * D_PI;
static constexpr double D_TAU = 12.0 / ((double)MM * (double)MM);
static constexpr double D_INV4TAU = 1.0 / (4.0 * D_TAU);
// scale/M^2 = 1/(8*pi^2*M^4) folded into W tables
static constexpr double D_F = 1.0 / (8.0 * D_PI * D_PI * (double)MM * (double)MM * (double)MM * (double)MM);

__device__ __forceinline__ void cmac(float2& acc, float2 a, float2 b) {
    acc.x = fmaf(a.x, b.x, fmaf(-a.y, b.y, acc.x));
    acc.y = fmaf(a.x, b.y, fmaf( a.y, b.x, acc.y));
}

// ---------------------------------------------------------------------------
// Kernel 0: zero S accumulator + out (both are atomicAdd targets).
// ---------------------------------------------------------------------------
#define S_FLOATS (NB * KP * KP * 2)
#define OUT_FLOATS (NB * NP * 2)
__global__ __launch_bounds__(256) void k_zero(float* __restrict__ S,
                                              float* __restrict__ out) {
    int i = blockIdx.x * 256 + threadIdx.x;
    int stride = gridDim.x * 256;
    for (int j = i; j < S_FLOATS; j += stride) S[j] = 0.f;
    for (int j = i; j < OUT_FLOATS; j += stride) out[j] = 0.f;
}

// ---------------------------------------------------------------------------
// Kernel 1: per-point Gaussian sampling + length-129 DFT via register twiddle
// rotation (resynced exactly every 16 steps from integer (kc*a) mod M).
// Inner loop: 1 broadcast LDS read + 8 FMA, no twiddle table.
// ---------------------------------------------------------------------------
__global__ __launch_bounds__(128) void k_dft(const float* __restrict__ x,
                                             float2* __restrict__ A,
                                             float2* __restrict__ B) {
    const int bp  = blockIdx.x;       // b*512+p
    const int tid = threadIdx.x;
    const float x0 = x[bp * 2 + 0];
    const float x1 = x[bp * 2 + 1];

    __shared__ float2 g2[MM];   // (ga, gb)
    const float inv4tau = (float)D_INV4TAU;
    const float Lf      = (float)D_L;
    for (int a = tid; a < MM; a += 128) {
        float u  = (float)a * (float)(D_L / MM);
        float d0 = x0 - u, d1 = x1 - u;
        float ga = expf(-d0 * d0 * inv4tau)
                 + expf(-(d0 - Lf) * (d0 - Lf) * inv4tau)
                 + expf(-(d0 + Lf) * (d0 + Lf) * inv4tau);
        float gb = expf(-d1 * d1 * inv4tau)
                 + expf(-(d1 - Lf) * (d1 - Lf) * inv4tau)
                 + expf(-(d1 + Lf) * (d1 + Lf) * inv4tau);
        g2[a] = make_float2(ga, gb);
    }
    __syncthreads();

    const size_t base = (size_t)bp * KP;
    const float nf = (float)(-2.0 * D_PI / MM);
    for (int k = tid; k < KP; k += 128) {
        float Ar = 0.f, Ai = 0.f, Br = 0.f, Bi = 0.f;
        if (k < MM) {
            int kc  = k - 64;
            int kcm = (kc < 0) ? kc + MM : kc;          // kc mod M in [0,M)
            float sw, cw;
            __sincosf(nf * (float)kcm, &sw, &cw);       // w = exp(-2pi*i*kc/M)
            const int step16 = (kcm * 16) % MM;
            int idx = 0;                                 // (kcm*a) mod M at chunk start
            for (int c = 0; c < 128; c += 16) {
                float st, ct;
                __sincosf(nf * (float)idx, &st, &ct);    // exact resync
                float tx = ct, ty = st;
                #pragma unroll
                for (int j = 0; j < 16; ++j) {
                    float2 g = g2[c + j];                // broadcast (same addr all lanes)
                    Ar = fmaf(g.x, tx, Ar); Ai = fmaf(g.x, ty, Ai);
                    Br = fmaf(g.y, tx, Br); Bi = fmaf(g.y, ty, Bi);
                    float nx = tx * cw - ty * sw;
                    float ny = tx * sw + ty * cw;
                    tx = nx; ty = ny;
                }
                idx += step16; if (idx >= MM) idx -= MM;
            }
            {   // a = 128 tail
                float st, ct;
                __sincosf(nf * (float)idx, &st, &ct);
                float2 g = g2[128];
                Ar = fmaf(g.x, ct, Ar); Ai = fmaf(g.x, st, Ai);
                Br = fmaf(g.y, ct, Br); Bi = fmaf(g.y, st, Bi);
            }
        }
        A[base + k] = make_float2(Ar, Ai);
        B[base + k] = make_float2(Br, Bi);
    }
}

// ---------------------------------------------------------------------------
// Kernel 2: packed W table (w0,w1) per (m,n), with global factor folded in.
// ---------------------------------------------------------------------------
__global__ __launch_bounds__(256) void k_w(const float* __restrict__ s0p,
                                           const float* __restrict__ s1p,
                                           const float* __restrict__ a0p,
                                           const float* __restrict__ a1p,
                                           float2* __restrict__ Wp) {
    int i = blockIdx.x * 256 + threadIdx.x;
    if (i >= KP * KP) return;
    int m = i / KP, n = i % KP;
    float w0 = 0.f, w1 = 0.f;
    if (m < MM && n < MM) {
        float kx = (float)(m - 64), ky = (float)(n - 64);
        float k2  = kx * kx + ky * ky;
        float dec = (float)(D_PI / D_TAU) * expf(k2 * (float)D_TAU);
        float base = dec * dec * (float)(4.0 * D_PI * D_F);
        float s0 = s0p[0], s1 = s1p[0];   // mu0 = mu1 = 1
        w0 = a0p[0] * base / (k2 + s0 * s0);
        w1 = a1p[0] * base / (k2 + s1 * s1);
    }
    Wp[i] = make_float2(w0, w1);
}

// ---------------------------------------------------------------------------
// Kernel 3: S_b[m,n] += sum_{p in chunk} A[b,p,m]*B[b,p,n]
// Grid: (33 m-tiles, 16 p-chunks, 4 batches) = 2112 blocks, 128 threads.
// n = tid covers 0..127; n=128 column handled by lanes 0..3 (1 cmac/p).
// p unrolled x4 with explicit next-group prefetch (latency hiding).
// ---------------------------------------------------------------------------
#define PCHUNK 32
__global__ __launch_bounds__(128) void k_s(const float2* __restrict__ A,
                                           const float2* __restrict__ B,
                                           float2* __restrict__ S) {
    const int b   = blockIdx.z;
    const int p0  = blockIdx.y * PCHUNK;
    const int m0  = blockIdx.x * 4;
    const int tid = threadIdx.x;

    const float2* __restrict__ Ab = A + (size_t)b * NP * KP;
    const float2* __restrict__ Bb = B + (size_t)b * NP * KP;

    float2 acc[4];
    #pragma unroll
    for (int i = 0; i < 4; ++i) acc[i] = make_float2(0.f, 0.f);
    float2 acc2 = make_float2(0.f, 0.f);   // partial for S[m0+tid][128], lanes 0..3

    float2 v[4], am[4][4], as[4], bu[4];
    #pragma unroll
    for (int i = 0; i < 4; ++i) {
        const size_t r = (size_t)(p0 + i) * KP;
        v[i]  = Bb[r + tid];
        bu[i] = Bb[r + 128];                 // wave-uniform
        as[i] = Ab[r + m0 + (tid & 3)];      // per-lane A for the n=128 path
        #pragma unroll
        for (int j = 0; j < 4; ++j) am[i][j] = Ab[r + m0 + j];   // wave-uniform
    }

    for (int pg = 0; pg < PCHUNK; pg += 4) {
        float2 nv[4], nam[4][4], nas[4], nbu[4];
        const bool more = (pg + 4 < PCHUNK);
        if (more) {
            #pragma unroll
            for (int i = 0; i < 4; ++i) {
                const size_t r = (size_t)(p0 + pg + 4 + i) * KP;
                nv[i]  = Bb[r + tid];
                nbu[i] = Bb[r + 128];
                nas[i] = Ab[r + m0 + (tid & 3)];
                #pragma unroll
                for (int j = 0; j < 4; ++j) nam[i][j] = Ab[r + m0 + j];
            }
        }
        #pragma unroll
        for (int i = 0; i < 4; ++i) {
            cmac(acc[0], am[i][0], v[i]);
            cmac(acc[1], am[i][1], v[i]);
            cmac(acc[2], am[i][2], v[i]);
            cmac(acc[3], am[i][3], v[i]);
        }
        if (tid < 4) {
            #pragma unroll
            for (int i = 0; i < 4; ++i) cmac(acc2, as[i], bu[i]);
        }
        if (more) {
            #pragma unroll
            for (int i = 0; i < 4; ++i) {
                v[i] = nv[i]; bu[i] = nbu[i]; as[i] = nas[i];
                #pragma unroll
                for (int j = 0; j < 4; ++j) am[i][j] = nam[i][j];
            }
        }
    }

    float* Sb = (float*)(S + (size_t)b * KP * KP);
    #pragma unroll
    for (int i = 0; i < 4; ++i) {
        atomicAdd(&Sb[((size_t)(m0 + i) * KP + tid) * 2 + 0], acc[i].x);
        atomicAdd(&Sb[((size_t)(m0 + i) * KP + tid) * 2 + 1], acc[i].y);
    }
    if (tid < 4) {
        atomicAdd(&Sb[((size_t)(m0 + tid) * KP + 128) * 2 + 0], acc2.x);
        atomicAdd(&Sb[((size_t)(m0 + tid) * KP + 128) * 2 + 1], acc2.y);
    }
}

// ---------------------------------------------------------------------------
// Kernel 4: per point p (8 per block), both channels, m-chunked over 8 blocks:
//   e_c += sum_{m in chunk, n<=128} W_c[m,n]*( Re(S*conj(A_m B_n)) - |A_m B_n|^2 )
// bb[pi] = sB[pi][tid] hoisted (n fixed per thread); S/W rows prefetched.
// ---------------------------------------------------------------------------
#define MCHUNK 17
__global__ __launch_bounds__(128) void k_final(const float2* __restrict__ A,
                                               const float2* __restrict__ B,
                                               const float2* __restrict__ S,
                                               const float2* __restrict__ Wp,
                                               float* __restrict__ out) {
    const int b      = blockIdx.z;
    const int mstart = blockIdx.y * MCHUNK;
    const int mend   = (mstart + MCHUNK < MM) ? (mstart + MCHUNK) : MM;
    const int p0     = blockIdx.x * 8;
    const int tid    = threadIdx.x;

    __shared__ float2 sB[8][KP];
    __shared__ float2 sAT[KP][8];
    #pragma unroll
    for (int pi = 0; pi < 8; ++pi) {
        const size_t g = (size_t)(b * NP + p0 + pi) * KP;
        for (int k = tid; k < KP; k += 128) {
            sB[pi][k]  = B[g + k];
            sAT[k][pi] = A[g + k];
        }
    }
    __syncthreads();

    float2 bb[8];
    #pragma unroll
    for (int pi = 0; pi < 8; ++pi) bb[pi] = sB[pi][tid];

    float e0[8], e1[8];
    #pragma unroll
    for (int i = 0; i < 8; ++i) { e0[i] = 0.f; e1[i] = 0.f; }

    const float2* __restrict__ Sb = S + (size_t)b * KP * KP;
    float2 s = Sb[(size_t)mstart * KP + tid];
    float2 w = Wp[(size_t)mstart * KP + tid];
    for (int m = mstart; m < mend; ++m) {
        float2 sn = s, wn = w;
        if (m + 1 < mend) {
            sn = Sb[(size_t)(m + 1) * KP + tid];
            wn = Wp[(size_t)(m + 1) * KP + tid];
        }
        #pragma unroll
        for (int pi = 0; pi < 8; ++pi) {
            float2 a  = sAT[m][pi];           // broadcast
            float2 bv = bb[pi];
            float abr = a.x * bv.x - a.y * bv.y;
            float abi = a.x * bv.y + a.y * bv.x;
            float d   = fmaf(s.x, abr, s.y * abi) - fmaf(abr, abr, abi * abi);
            e0[pi] = fmaf(w.x, d, e0[pi]);
            e1[pi] = fmaf(w.y, d, e1[pi]);
        }
        s = sn; w = wn;
    }
    // n = 128 column: thread tid handles m = mstart + tid
    if (tid < mend - mstart) {
        const int m = mstart + tid;
        float2 s8 = Sb[(size_t)m * KP + 128];
        float2 w8 = Wp[(size_t)m * KP + 128];
        #pragma unroll
        for (int pi = 0; pi < 8; ++pi) {
            float2 a  = sAT[m][pi];
            float2 bv = sB[pi][128];
            float abr = a.x * bv.x - a.y * bv.y;
            float abi = a.x * bv.y + a.y * bv.x;
            float d   = fmaf(s8.x, abr, s8.y * abi) - fmaf(abr, abr, abi * abi);
            e0[pi] = fmaf(w8.x, d, e0[pi]);
            e1[pi] = fmaf(w8.y, d, e1[pi]);
        }
    }

    // reduce 128 threads -> 16 partials (8 points x 2 channels), atomic to out
    const int lane = tid & 63, wv = tid >> 6;
    __shared__ float part[2][16];
    #pragma unroll
    for (int pi = 0; pi < 8; ++pi) {
        float r0 = e0[pi], r1 = e1[pi];
        #pragma unroll
        for (int o = 32; o > 0; o >>= 1) {
            r0 += __shfl_down(r0, o, 64);
            r1 += __shfl_down(r1, o, 64);
        }
        if (lane == 0) { part[wv][pi * 2 + 0] = r0; part[wv][pi * 2 + 1] = r1; }
    }
    __syncthreads();
    if (tid < 16) {
        float r = part[0][tid] + part[1][tid];
        int pi = tid >> 1, c = tid & 1;
        atomicAdd(&out[((size_t)(b * NP + p0 + pi)) * 2 + c], r);
    }
}

// ---------------------------------------------------------------------------
extern "C" void kernel_launch(void* const* d_in, const int* in_sizes, int n_in,
                              void* d_out, int out_size, void* d_ws, size_t ws_size,
                              hipStream_t stream) {
    const float* x      = (const float*)d_in[0];
    const float* shift0 = (const float*)d_in[1];
    const float* shift1 = (const float*)d_in[2];
    const float* amp0   = (const float*)d_in[3];
    const float* amp1   = (const float*)d_in[4];
    float* out = (float*)d_out;

    // workspace layout (float2-aligned)
    float2* A  = (float2*)d_ws;                 // [NB][NP][KP]
    float2* Bv = A + (size_t)NB * NP * KP;      // [NB][NP][KP]
    float2* S  = Bv + (size_t)NB * NP * KP;     // [NB][KP][KP]
    float2* Wp = S + (size_t)NB * KP * KP;      // [KP*KP] packed (w0,w1)

    k_zero<<<256, 256, 0, stream>>>((float*)S, out);
    k_dft<<<NB * NP, 128, 0, stream>>>(x, A, Bv);
    k_w<<<(KP * KP + 255) / 256, 256, 0, stream>>>(shift0, shift1, amp0, amp1, Wp);
    k_s<<<dim3(KP / 4, NP / PCHUNK, NB), 128, 0, stream>>>(A, Bv, S);
    k_final<<<dim3(NP / 8, 8, NB), 128, 0, stream>>>(A, Bv, S, Wp, out);
}

// Round 4
// 134.784 us; speedup vs baseline: 1.1948x; 1.1948x over previous
//
#include <hip/hip_runtime.h>
#include <math.h>

// Problem constants (from reference)
#define MM 129      // mesh points per axis (odd)
#define KP 132      // padded K dim (pad entries zero)
#define NP 512      // points per batch
#define NB 4        // batches

static constexpr double D_PI  = 3.14159265358979323846;
static constexpr double D_L   = 2.0 * D_PI;
static constexpr double D_TAU = 12.0 / ((double)MM * (double)MM);
static constexpr double D_INV4TAU = 1.0 / (4.0 * D_TAU);
// scale/M^2 = 1/(8*pi^2*M^4) folded into W tables
static constexpr double D_F = 1.0 / (8.0 * D_PI * D_PI * (double)MM * (double)MM * (double)MM * (double)MM);

__device__ __forceinline__ void cmac(float2& acc, float2 a, float2 b) {
    acc.x = fmaf(a.x, b.x, fmaf(-a.y, b.y, acc.x));
    acc.y = fmaf(a.x, b.y, fmaf( a.y, b.x, acc.y));
}

// ---------------------------------------------------------------------------
// Kernel 0: zero S accumulator + out (both are atomicAdd targets).
// ---------------------------------------------------------------------------
#define S_FLOATS (NB * KP * KP * 2)
#define OUT_FLOATS (NB * NP * 2)
__global__ __launch_bounds__(256) void k_zero(float* __restrict__ S,
                                              float* __restrict__ out) {
    int i = blockIdx.x * 256 + threadIdx.x;
    int stride = gridDim.x * 256;
    for (int j = i; j < S_FLOATS; j += stride) S[j] = 0.f;
    for (int j = i; j < OUT_FLOATS; j += stride) out[j] = 0.f;
}

// ---------------------------------------------------------------------------
// Kernel 1a: twiddle table Tw[a][k] = exp(-2pi*i*kc*a/M), kc = k-64, k<129.
// 129 x 132 float2 (~136 KB), L2-resident, broadcast-read by all k_dft blocks.
// Phase reduced exactly in integers -> fp32 trig on small args.
// ---------------------------------------------------------------------------
__global__ __launch_bounds__(256) void k_tw(float2* __restrict__ Tw) {
    int i = blockIdx.x * 256 + threadIdx.x;
    if (i >= MM * KP) return;
    int a = i / KP, k = i % KP;
    float2 v = make_float2(0.f, 0.f);
    if (k < MM) {
        int kcm = k - 64; if (kcm < 0) kcm += MM;
        int ph  = (kcm * a) % MM;
        float th = (float)(-2.0 * D_PI / MM) * (float)ph;
        float s, c;
        __sincosf(th, &s, &c);
        v = make_float2(c, s);
    }
    Tw[i] = v;
}

// ---------------------------------------------------------------------------
// Kernel 1b: per-point Gaussian sampling + length-129 DFT, table-driven.
// 4 points/block, 512 blocks x 128 threads. tid = k (0..127).
// Inner loop: 1 coalesced Tw load + 2 broadcast ds_read_b128 + 16 indep FMA.
// k=128 via in-block shuffle reduction; k=129..131 zero pad.
// ---------------------------------------------------------------------------
#define PPB 4
__global__ __launch_bounds__(128) void k_dft(const float* __restrict__ x,
                                             const float2* __restrict__ Tw,
                                             float2* __restrict__ A,
                                             float2* __restrict__ B) {
    const int p0  = blockIdx.x * PPB;    // global point index (b*NP+p)
    const int tid = threadIdx.x;

    __shared__ float sGa[MM * PPB];      // a-major: sGa[a*4+pt]
    __shared__ float sGb[MM * PPB];
    __shared__ float red[2][16];

    const float inv4tau = (float)D_INV4TAU;
    const float Lf      = (float)D_L;
    for (int idx = tid; idx < MM * PPB; idx += 128) {
        int pt = idx & 3, a = idx >> 2;
        float x0 = x[(p0 + pt) * 2 + 0];
        float x1 = x[(p0 + pt) * 2 + 1];
        float u  = (float)a * (float)(D_L / MM);
        float d0 = x0 - u, d1 = x1 - u;
        sGa[idx] = expf(-d0 * d0 * inv4tau)
                 + expf(-(d0 - Lf) * (d0 - Lf) * inv4tau)
                 + expf(-(d0 + Lf) * (d0 + Lf) * inv4tau);
        sGb[idx] = expf(-d1 * d1 * inv4tau)
                 + expf(-(d1 - Lf) * (d1 - Lf) * inv4tau)
                 + expf(-(d1 + Lf) * (d1 + Lf) * inv4tau);
    }
    __syncthreads();

    float Ar[PPB], Ai[PPB], Br[PPB], Bi[PPB];
    #pragma unroll
    for (int pt = 0; pt < PPB; ++pt) { Ar[pt] = Ai[pt] = Br[pt] = Bi[pt] = 0.f; }

    #pragma unroll 4
    for (int a = 0; a < MM; ++a) {
        float2 t  = Tw[a * KP + tid];                       // coalesced, L1/L2
        float4 ga = *(const float4*)&sGa[a * 4];            // broadcast b128
        float4 gb = *(const float4*)&sGb[a * 4];
        Ar[0] = fmaf(ga.x, t.x, Ar[0]); Ai[0] = fmaf(ga.x, t.y, Ai[0]);
        Br[0] = fmaf(gb.x, t.x, Br[0]); Bi[0] = fmaf(gb.x, t.y, Bi[0]);
        Ar[1] = fmaf(ga.y, t.x, Ar[1]); Ai[1] = fmaf(ga.y, t.y, Ai[1]);
        Br[1] = fmaf(gb.y, t.x, Br[1]); Bi[1] = fmaf(gb.y, t.y, Bi[1]);
        Ar[2] = fmaf(ga.z, t.x, Ar[2]); Ai[2] = fmaf(ga.z, t.y, Ai[2]);
        Br[2] = fmaf(gb.z, t.x, Br[2]); Bi[2] = fmaf(gb.z, t.y, Bi[2]);
        Ar[3] = fmaf(ga.w, t.x, Ar[3]); Ai[3] = fmaf(ga.w, t.y, Ai[3]);
        Br[3] = fmaf(gb.w, t.x, Br[3]); Bi[3] = fmaf(gb.w, t.y, Bi[3]);
    }

    #pragma unroll
    for (int pt = 0; pt < PPB; ++pt) {
        const size_t base = (size_t)(p0 + pt) * KP;
        A[base + tid] = make_float2(Ar[pt], Ai[pt]);
        B[base + tid] = make_float2(Br[pt], Bi[pt]);
    }

    // ----- k = 128 (kc=+64): reduce over a across the block -----
    const int lane = tid & 63, wv = tid >> 6;
    float2 t1   = Tw[tid * KP + 128];   // a = tid (scattered, one-time)
    float2 t128 = Tw[128 * KP + 128];
    #pragma unroll
    for (int pt = 0; pt < PPB; ++pt) {
        float ga = sGa[tid * 4 + pt], gb = sGb[tid * 4 + pt];
        float ar = ga * t1.x, ai = ga * t1.y;
        float br = gb * t1.x, bi = gb * t1.y;
        if (tid == 0) {   // a = 128 term
            float ga8 = sGa[128 * 4 + pt], gb8 = sGb[128 * 4 + pt];
            ar = fmaf(ga8, t128.x, ar); ai = fmaf(ga8, t128.y, ai);
            br = fmaf(gb8, t128.x, br); bi = fmaf(gb8, t128.y, bi);
        }
        #pragma unroll
        for (int o = 32; o > 0; o >>= 1) {
            ar += __shfl_down(ar, o, 64); ai += __shfl_down(ai, o, 64);
            br += __shfl_down(br, o, 64); bi += __shfl_down(bi, o, 64);
        }
        if (lane == 0) {
            red[wv][pt * 4 + 0] = ar; red[wv][pt * 4 + 1] = ai;
            red[wv][pt * 4 + 2] = br; red[wv][pt * 4 + 3] = bi;
        }
    }
    __syncthreads();
    if (tid < 8) {
        int pt = tid >> 1, isB = tid & 1;
        float re = red[0][pt * 4 + isB * 2 + 0] + red[1][pt * 4 + isB * 2 + 0];
        float im = red[0][pt * 4 + isB * 2 + 1] + red[1][pt * 4 + isB * 2 + 1];
        float2* dst = isB ? B : A;
        dst[(size_t)(p0 + pt) * KP + 128] = make_float2(re, im);
    }
    // ----- k = 129..131 zero pad -----
    if (tid < 3) {
        #pragma unroll
        for (int pt = 0; pt < PPB; ++pt) {
            const size_t base = (size_t)(p0 + pt) * KP;
            A[base + 129 + tid] = make_float2(0.f, 0.f);
            B[base + 129 + tid] = make_float2(0.f, 0.f);
        }
    }
}

// ---------------------------------------------------------------------------
// Kernel 2: packed W table (w0,w1) per (m,n), with global factor folded in.
// ---------------------------------------------------------------------------
__global__ __launch_bounds__(256) void k_w(const float* __restrict__ s0p,
                                           const float* __restrict__ s1p,
                                           const float* __restrict__ a0p,
                                           const float* __restrict__ a1p,
                                           float2* __restrict__ Wp) {
    int i = blockIdx.x * 256 + threadIdx.x;
    if (i >= KP * KP) return;
    int m = i / KP, n = i % KP;
    float w0 = 0.f, w1 = 0.f;
    if (m < MM && n < MM) {
        float kx = (float)(m - 64), ky = (float)(n - 64);
        float k2  = kx * kx + ky * ky;
        float dec = (float)(D_PI / D_TAU) * expf(k2 * (float)D_TAU);
        float base = dec * dec * (float)(4.0 * D_PI * D_F);
        float s0 = s0p[0], s1 = s1p[0];   // mu0 = mu1 = 1
        w0 = a0p[0] * base / (k2 + s0 * s0);
        w1 = a1p[0] * base / (k2 + s1 * s1);
    }
    Wp[i] = make_float2(w0, w1);
}

// ---------------------------------------------------------------------------
// Kernel 3: S_b[m,n] += sum_{p in chunk} A[b,p,m]*B[b,p,n]
// Grid: (33 m-tiles, 16 p-chunks, 4 batches) = 2112 blocks, 128 threads.
// n = tid covers 0..127; n=128 column handled by lanes 0..3 (1 cmac/p).
// p unrolled x4 with explicit next-group prefetch (latency hiding).
// ---------------------------------------------------------------------------
#define PCHUNK 32
__global__ __launch_bounds__(128) void k_s(const float2* __restrict__ A,
                                           const float2* __restrict__ B,
                                           float2* __restrict__ S) {
    const int b   = blockIdx.z;
    const int p0  = blockIdx.y * PCHUNK;
    const int m0  = blockIdx.x * 4;
    const int tid = threadIdx.x;

    const float2* __restrict__ Ab = A + (size_t)b * NP * KP;
    const float2* __restrict__ Bb = B + (size_t)b * NP * KP;

    float2 acc[4];
    #pragma unroll
    for (int i = 0; i < 4; ++i) acc[i] = make_float2(0.f, 0.f);
    float2 acc2 = make_float2(0.f, 0.f);   // partial for S[m0+tid][128], lanes 0..3

    float2 v[4], am[4][4], as[4], bu[4];
    #pragma unroll
    for (int i = 0; i < 4; ++i) {
        const size_t r = (size_t)(p0 + i) * KP;
        v[i]  = Bb[r + tid];
        bu[i] = Bb[r + 128];                 // wave-uniform
        as[i] = Ab[r + m0 + (tid & 3)];      // per-lane A for the n=128 path
        #pragma unroll
        for (int j = 0; j < 4; ++j) am[i][j] = Ab[r + m0 + j];   // wave-uniform
    }

    for (int pg = 0; pg < PCHUNK; pg += 4) {
        float2 nv[4], nam[4][4], nas[4], nbu[4];
        const bool more = (pg + 4 < PCHUNK);
        if (more) {
            #pragma unroll
            for (int i = 0; i < 4; ++i) {
                const size_t r = (size_t)(p0 + pg + 4 + i) * KP;
                nv[i]  = Bb[r + tid];
                nbu[i] = Bb[r + 128];
                nas[i] = Ab[r + m0 + (tid & 3)];
                #pragma unroll
                for (int j = 0; j < 4; ++j) nam[i][j] = Ab[r + m0 + j];
            }
        }
        #pragma unroll
        for (int i = 0; i < 4; ++i) {
            cmac(acc[0], am[i][0], v[i]);
            cmac(acc[1], am[i][1], v[i]);
            cmac(acc[2], am[i][2], v[i]);
            cmac(acc[3], am[i][3], v[i]);
        }
        if (tid < 4) {
            #pragma unroll
            for (int i = 0; i < 4; ++i) cmac(acc2, as[i], bu[i]);
        }
        if (more) {
            #pragma unroll
            for (int i = 0; i < 4; ++i) {
                v[i] = nv[i]; bu[i] = nbu[i]; as[i] = nas[i];
                #pragma unroll
                for (int j = 0; j < 4; ++j) am[i][j] = nam[i][j];
            }
        }
    }

    float* Sb = (float*)(S + (size_t)b * KP * KP);
    #pragma unroll
    for (int i = 0; i < 4; ++i) {
        atomicAdd(&Sb[((size_t)(m0 + i) * KP + tid) * 2 + 0], acc[i].x);
        atomicAdd(&Sb[((size_t)(m0 + i) * KP + tid) * 2 + 1], acc[i].y);
    }
    if (tid < 4) {
        atomicAdd(&Sb[((size_t)(m0 + tid) * KP + 128) * 2 + 0], acc2.x);
        atomicAdd(&Sb[((size_t)(m0 + tid) * KP + 128) * 2 + 1], acc2.y);
    }
}

// ---------------------------------------------------------------------------
// Kernel 4: per point p (8 per block), both channels, m-chunked over 8 blocks:
//   e_c += sum_{m in chunk, n<=128} W_c[m,n]*( Re(S*conj(A_m B_n)) - |A_m B_n|^2 )
// bb[pi] = sB[pi][tid] hoisted (n fixed per thread); S/W rows prefetched.
// ---------------------------------------------------------------------------
#define MCHUNK 17
__global__ __launch_bounds__(128) void k_final(const float2* __restrict__ A,
                                               const float2* __restrict__ B,
                                               const float2* __restrict__ S,
                                               const float2* __restrict__ Wp,
                                               float* __restrict__ out) {
    const int b      = blockIdx.z;
    const int mstart = blockIdx.y * MCHUNK;
    const int mend   = (mstart + MCHUNK < MM) ? (mstart + MCHUNK) : MM;
    const int p0     = blockIdx.x * 8;
    const int tid    = threadIdx.x;

    __shared__ float2 sB[8][KP];
    __shared__ float2 sAT[KP][8];
    #pragma unroll
    for (int pi = 0; pi < 8; ++pi) {
        const size_t g = (size_t)(b * NP + p0 + pi) * KP;
        for (int k = tid; k < KP; k += 128) {
            sB[pi][k]  = B[g + k];
            sAT[k][pi] = A[g + k];
        }
    }
    __syncthreads();

    float2 bb[8];
    #pragma unroll
    for (int pi = 0; pi < 8; ++pi) bb[pi] = sB[pi][tid];

    float e0[8], e1[8];
    #pragma unroll
    for (int i = 0; i < 8; ++i) { e0[i] = 0.f; e1[i] = 0.f; }

    const float2* __restrict__ Sb = S + (size_t)b * KP * KP;
    float2 s = Sb[(size_t)mstart * KP + tid];
    float2 w = Wp[(size_t)mstart * KP + tid];
    for (int m = mstart; m < mend; ++m) {
        float2 sn = s, wn = w;
        if (m + 1 < mend) {
            sn = Sb[(size_t)(m + 1) * KP + tid];
            wn = Wp[(size_t)(m + 1) * KP + tid];
        }
        #pragma unroll
        for (int pi = 0; pi < 8; ++pi) {
            float2 a  = sAT[m][pi];           // broadcast
            float2 bv = bb[pi];
            float abr = a.x * bv.x - a.y * bv.y;
            float abi = a.x * bv.y + a.y * bv.x;
            float d   = fmaf(s.x, abr, s.y * abi) - fmaf(abr, abr, abi * abi);
            e0[pi] = fmaf(w.x, d, e0[pi]);
            e1[pi] = fmaf(w.y, d, e1[pi]);
        }
        s = sn; w = wn;
    }
    // n = 128 column: thread tid handles m = mstart + tid
    if (tid < mend - mstart) {
        const int m = mstart + tid;
        float2 s8 = Sb[(size_t)m * KP + 128];
        float2 w8 = Wp[(size_t)m * KP + 128];
        #pragma unroll
        for (int pi = 0; pi < 8; ++pi) {
            float2 a  = sAT[m][pi];
            float2 bv = sB[pi][128];
            float abr = a.x * bv.x - a.y * bv.y;
            float abi = a.x * bv.y + a.y * bv.x;
            float d   = fmaf(s8.x, abr, s8.y * abi) - fmaf(abr, abr, abi * abi);
            e0[pi] = fmaf(w8.x, d, e0[pi]);
            e1[pi] = fmaf(w8.y, d, e1[pi]);
        }
    }

    // reduce 128 threads -> 16 partials (8 points x 2 channels), atomic to out
    const int lane = tid & 63, wv = tid >> 6;
    __shared__ float part[2][16];
    #pragma unroll
    for (int pi = 0; pi < 8; ++pi) {
        float r0 = e0[pi], r1 = e1[pi];
        #pragma unroll
        for (int o = 32; o > 0; o >>= 1) {
            r0 += __shfl_down(r0, o, 64);
            r1 += __shfl_down(r1, o, 64);
        }
        if (lane == 0) { part[wv][pi * 2 + 0] = r0; part[wv][pi * 2 + 1] = r1; }
    }
    __syncthreads();
    if (tid < 16) {
        float r = part[0][tid] + part[1][tid];
        int pi = tid >> 1, c = tid & 1;
        atomicAdd(&out[((size_t)(b * NP + p0 + pi)) * 2 + c], r);
    }
}

// ---------------------------------------------------------------------------
extern "C" void kernel_launch(void* const* d_in, const int* in_sizes, int n_in,
                              void* d_out, int out_size, void* d_ws, size_t ws_size,
                              hipStream_t stream) {
    const float* x      = (const float*)d_in[0];
    const float* shift0 = (const float*)d_in[1];
    const float* shift1 = (const float*)d_in[2];
    const float* amp0   = (const float*)d_in[3];
    const float* amp1   = (const float*)d_in[4];
    float* out = (float*)d_out;

    // workspace layout (float2-aligned)
    float2* A  = (float2*)d_ws;                 // [NB][NP][KP]
    float2* Bv = A + (size_t)NB * NP * KP;      // [NB][NP][KP]
    float2* S  = Bv + (size_t)NB * NP * KP;     // [NB][KP][KP]
    float2* Wp = S + (size_t)NB * KP * KP;      // [KP*KP] packed (w0,w1)
    float2* Tw = Wp + (size_t)KP * KP;          // [MM*KP] twiddle table

    k_zero<<<256, 256, 0, stream>>>((float*)S, out);
    k_tw<<<(MM * KP + 255) / 256, 256, 0, stream>>>(Tw);
    k_w<<<(KP * KP + 255) / 256, 256, 0, stream>>>(shift0, shift1, amp0, amp1, Wp);
    k_dft<<<(NB * NP) / PPB, 128, 0, stream>>>(x, Tw, A, Bv);
    k_s<<<dim3(KP / 4, NP / PCHUNK, NB), 128, 0, stream>>>(A, Bv, S);
    k_final<<<dim3(NP / 8, 8, NB), 128, 0, stream>>>(A, Bv, S, Wp, out);
}

// Round 5
// 128.284 us; speedup vs baseline: 1.2553x; 1.0507x over previous
//
#include <hip/hip_runtime.h>
#include <math.h>

// Problem constants (from reference)
#define MM 129      // mesh points per axis (odd)
#define KP 132      // padded K dim (pad entries zero)
#define NP 512      // points per batch
#define NB 4        // batches

static constexpr double D_PI  = 3.14159265358979323846;
static constexpr double D_L   = 2.0 * D_PI;
static constexpr double D_TAU = 12.0 / ((double)MM * (double)MM);
static constexpr double D_INV4TAU = 1.0 / (4.0 * D_TAU);
// scale/M^2 = 1/(8*pi^2*M^4) folded into W tables
static constexpr double D_F = 1.0 / (8.0 * D_PI * D_PI * (double)MM * (double)MM * (double)MM * (double)MM);

__device__ __forceinline__ void cmac(float2& acc, float2 a, float2 b) {
    acc.x = fmaf(a.x, b.x, fmaf(-a.y, b.y, acc.x));
    acc.y = fmaf(a.x, b.y, fmaf( a.y, b.x, acc.y));
}

// ---------------------------------------------------------------------------
// Kernel 0 (fused setup): zero S/out, build twiddle table Tw, build W table.
// All index ranges covered by one grid-stride pass each; total ~320 KB writes.
// ---------------------------------------------------------------------------
#define S_FLOATS (NB * KP * KP * 2)
#define OUT_FLOATS (NB * NP * 2)
__global__ __launch_bounds__(256) void k_setup(const float* __restrict__ s0p,
                                               const float* __restrict__ s1p,
                                               const float* __restrict__ a0p,
                                               const float* __restrict__ a1p,
                                               float* __restrict__ S,
                                               float* __restrict__ out,
                                               float2* __restrict__ Tw,
                                               float2* __restrict__ Wp) {
    const int i = blockIdx.x * 256 + threadIdx.x;
    const int stride = gridDim.x * 256;
    for (int j = i; j < S_FLOATS; j += stride) S[j] = 0.f;
    for (int j = i; j < OUT_FLOATS; j += stride) out[j] = 0.f;
    for (int j = i; j < MM * KP; j += stride) {
        int a = j / KP, k = j - (j / KP) * KP;
        float2 v = make_float2(0.f, 0.f);
        if (k < MM) {
            int kcm = k - 64; if (kcm < 0) kcm += MM;
            int ph  = (kcm * a) % MM;
            float th = (float)(-2.0 * D_PI / MM) * (float)ph;
            float s, c;
            __sincosf(th, &s, &c);
            v = make_float2(c, s);
        }
        Tw[j] = v;
    }
    for (int j = i; j < KP * KP; j += stride) {
        int m = j / KP, n = j - (j / KP) * KP;
        float w0 = 0.f, w1 = 0.f;
        if (m < MM && n < MM) {
            float kx = (float)(m - 64), ky = (float)(n - 64);
            float k2   = kx * kx + ky * ky;
            float dec  = (float)(D_PI / D_TAU) * expf(k2 * (float)D_TAU);
            float base = dec * dec * (float)(4.0 * D_PI * D_F);
            float s0 = s0p[0], s1 = s1p[0];   // mu0 = mu1 = 1
            w0 = a0p[0] * base / (k2 + s0 * s0);
            w1 = a1p[0] * base / (k2 + s1 * s1);
        }
        Wp[j] = make_float2(w0, w1);
    }
}

// ---------------------------------------------------------------------------
// Kernel 1: per-point Gaussian sampling + length-129 DFT, table-driven.
// 2 points/block, 1024 blocks (4 blocks/CU, 8 waves/CU) x 128 threads, tid=k.
// Inner loop: 1 coalesced 8B Tw load + 1 broadcast b128 LDS read + 8 indep FMA.
// k=128 via in-block shuffle reduction; k=129..131 zero pad.
// ---------------------------------------------------------------------------
#define PPB 2
__global__ __launch_bounds__(128) void k_dft(const float* __restrict__ x,
                                             const float2* __restrict__ Tw,
                                             float2* __restrict__ A,
                                             float2* __restrict__ B) {
    const int p0  = blockIdx.x * PPB;    // global point index (b*NP+p)
    const int tid = threadIdx.x;

    __shared__ float4 sG[MM];            // (ga_p0, gb_p0, ga_p1, gb_p1)
    __shared__ float red[2][8];

    const float inv4tau = (float)D_INV4TAU;
    const float Lf      = (float)D_L;
    for (int idx = tid; idx < MM * PPB; idx += 128) {
        int pt = idx & 1, a = idx >> 1;
        float x0 = x[(p0 + pt) * 2 + 0];
        float x1 = x[(p0 + pt) * 2 + 1];
        float u  = (float)a * (float)(D_L / MM);
        float d0 = x0 - u, d1 = x1 - u;
        float ga = expf(-d0 * d0 * inv4tau)
                 + expf(-(d0 - Lf) * (d0 - Lf) * inv4tau)
                 + expf(-(d0 + Lf) * (d0 + Lf) * inv4tau);
        float gb = expf(-d1 * d1 * inv4tau)
                 + expf(-(d1 - Lf) * (d1 - Lf) * inv4tau)
                 + expf(-(d1 + Lf) * (d1 + Lf) * inv4tau);
        ((float2*)&sG[a])[pt] = make_float2(ga, gb);   // contiguous b64, no conflict
    }
    __syncthreads();

    float Ar0 = 0.f, Ai0 = 0.f, Br0 = 0.f, Bi0 = 0.f;
    float Ar1 = 0.f, Ai1 = 0.f, Br1 = 0.f, Bi1 = 0.f;

    #pragma unroll 4
    for (int a = 0; a < MM; ++a) {
        float2 t = Tw[a * KP + tid];     // coalesced, L2-resident
        float4 g = sG[a];                // broadcast (same addr all lanes)
        Ar0 = fmaf(g.x, t.x, Ar0); Ai0 = fmaf(g.x, t.y, Ai0);
        Br0 = fmaf(g.y, t.x, Br0); Bi0 = fmaf(g.y, t.y, Bi0);
        Ar1 = fmaf(g.z, t.x, Ar1); Ai1 = fmaf(g.z, t.y, Ai1);
        Br1 = fmaf(g.w, t.x, Br1); Bi1 = fmaf(g.w, t.y, Bi1);
    }

    {
        const size_t b0 = (size_t)p0 * KP;
        const size_t b1 = (size_t)(p0 + 1) * KP;
        A[b0 + tid] = make_float2(Ar0, Ai0);
        B[b0 + tid] = make_float2(Br0, Bi0);
        A[b1 + tid] = make_float2(Ar1, Ai1);
        B[b1 + tid] = make_float2(Br1, Bi1);
    }

    // ----- k = 128 (kc=+64): reduce over a across the block -----
    const int lane = tid & 63, wv = tid >> 6;
    float2 t1   = Tw[tid * KP + 128];   // a = tid (scattered, one-time)
    float2 t128 = Tw[128 * KP + 128];
    float4 gt   = sG[tid];
    float4 g128 = sG[128];
    #pragma unroll
    for (int pt = 0; pt < PPB; ++pt) {
        float ga = pt ? gt.z : gt.x;
        float gb = pt ? gt.w : gt.y;
        float ar = ga * t1.x, ai = ga * t1.y;
        float br = gb * t1.x, bi = gb * t1.y;
        if (tid == 0) {   // a = 128 term
            float ga8 = pt ? g128.z : g128.x;
            float gb8 = pt ? g128.w : g128.y;
            ar = fmaf(ga8, t128.x, ar); ai = fmaf(ga8, t128.y, ai);
            br = fmaf(gb8, t128.x, br); bi = fmaf(gb8, t128.y, bi);
        }
        #pragma unroll
        for (int o = 32; o > 0; o >>= 1) {
            ar += __shfl_down(ar, o, 64); ai += __shfl_down(ai, o, 64);
            br += __shfl_down(br, o, 64); bi += __shfl_down(bi, o, 64);
        }
        if (lane == 0) {
            red[wv][pt * 4 + 0] = ar; red[wv][pt * 4 + 1] = ai;
            red[wv][pt * 4 + 2] = br; red[wv][pt * 4 + 3] = bi;
        }
        __syncthreads();
    }
    if (tid < 4) {
        int pt = tid >> 1, isB = tid & 1;
        float re = red[0][pt * 4 + isB * 2 + 0] + red[1][pt * 4 + isB * 2 + 0];
        float im = red[0][pt * 4 + isB * 2 + 1] + red[1][pt * 4 + isB * 2 + 1];
        float2* dst = isB ? B : A;
        dst[(size_t)(p0 + pt) * KP + 128] = make_float2(re, im);
    }
    // ----- k = 129..131 zero pad -----
    if (tid >= 4 && tid < 4 + 3 * PPB) {
        int t = tid - 4, pt = t / 3, k = 129 + (t % 3);
        const size_t base = (size_t)(p0 + pt) * KP;
        A[base + k] = make_float2(0.f, 0.f);
        B[base + k] = make_float2(0.f, 0.f);
    }
}

// ---------------------------------------------------------------------------
// Kernel 3: S_b[m,n] += sum_{p in chunk} A[b,p,m]*B[b,p,n]
// Grid: (33 m-tiles, 16 p-chunks, 4 batches) = 2112 blocks, 128 threads.
// n = tid covers 0..127; n=128 column handled by lanes 0..3 (1 cmac/p).
// p unrolled x4 with explicit next-group prefetch (latency hiding).
// ---------------------------------------------------------------------------
#define PCHUNK 32
__global__ __launch_bounds__(128) void k_s(const float2* __restrict__ A,
                                           const float2* __restrict__ B,
                                           float2* __restrict__ S) {
    const int b   = blockIdx.z;
    const int p0  = blockIdx.y * PCHUNK;
    const int m0  = blockIdx.x * 4;
    const int tid = threadIdx.x;

    const float2* __restrict__ Ab = A + (size_t)b * NP * KP;
    const float2* __restrict__ Bb = B + (size_t)b * NP * KP;

    float2 acc[4];
    #pragma unroll
    for (int i = 0; i < 4; ++i) acc[i] = make_float2(0.f, 0.f);
    float2 acc2 = make_float2(0.f, 0.f);   // partial for S[m0+tid][128], lanes 0..3

    float2 v[4], am[4][4], as[4], bu[4];
    #pragma unroll
    for (int i = 0; i < 4; ++i) {
        const size_t r = (size_t)(p0 + i) * KP;
        v[i]  = Bb[r + tid];
        bu[i] = Bb[r + 128];                 // wave-uniform
        as[i] = Ab[r + m0 + (tid & 3)];      // per-lane A for the n=128 path
        #pragma unroll
        for (int j = 0; j < 4; ++j) am[i][j] = Ab[r + m0 + j];   // wave-uniform
    }

    for (int pg = 0; pg < PCHUNK; pg += 4) {
        float2 nv[4], nam[4][4], nas[4], nbu[4];
        const bool more = (pg + 4 < PCHUNK);
        if (more) {
            #pragma unroll
            for (int i = 0; i < 4; ++i) {
                const size_t r = (size_t)(p0 + pg + 4 + i) * KP;
                nv[i]  = Bb[r + tid];
                nbu[i] = Bb[r + 128];
                nas[i] = Ab[r + m0 + (tid & 3)];
                #pragma unroll
                for (int j = 0; j < 4; ++j) nam[i][j] = Ab[r + m0 + j];
            }
        }
        #pragma unroll
        for (int i = 0; i < 4; ++i) {
            cmac(acc[0], am[i][0], v[i]);
            cmac(acc[1], am[i][1], v[i]);
            cmac(acc[2], am[i][2], v[i]);
            cmac(acc[3], am[i][3], v[i]);
        }
        if (tid < 4) {
            #pragma unroll
            for (int i = 0; i < 4; ++i) cmac(acc2, as[i], bu[i]);
        }
        if (more) {
            #pragma unroll
            for (int i = 0; i < 4; ++i) {
                v[i] = nv[i]; bu[i] = nbu[i]; as[i] = nas[i];
                #pragma unroll
                for (int j = 0; j < 4; ++j) am[i][j] = nam[i][j];
            }
        }
    }

    float* Sb = (float*)(S + (size_t)b * KP * KP);
    #pragma unroll
    for (int i = 0; i < 4; ++i) {
        atomicAdd(&Sb[((size_t)(m0 + i) * KP + tid) * 2 + 0], acc[i].x);
        atomicAdd(&Sb[((size_t)(m0 + i) * KP + tid) * 2 + 1], acc[i].y);
    }
    if (tid < 4) {
        atomicAdd(&Sb[((size_t)(m0 + tid) * KP + 128) * 2 + 0], acc2.x);
        atomicAdd(&Sb[((size_t)(m0 + tid) * KP + 128) * 2 + 1], acc2.y);
    }
}

// ---------------------------------------------------------------------------
// Kernel 4: per point p (8 per block), both channels, m-chunked over 8 blocks:
//   e_c += sum_{m in chunk, n<=128} W_c[m,n]*( Re(S*conj(A_m B_n)) - |A_m B_n|^2 )
// Staging: sA/sB indexed [pi][k] -> lane-consecutive LDS writes (conflict-free;
// the R3 transposed sAT[k][pi] layout was a 32-way write conflict).
// Reads sA[pi][m] are same-address broadcasts (free).
// ---------------------------------------------------------------------------
#define MCHUNK 17
__global__ __launch_bounds__(128) void k_final(const float2* __restrict__ A,
                                               const float2* __restrict__ B,
                                               const float2* __restrict__ S,
                                               const float2* __restrict__ Wp,
                                               float* __restrict__ out) {
    const int b      = blockIdx.z;
    const int mstart = blockIdx.y * MCHUNK;
    const int mend   = (mstart + MCHUNK < MM) ? (mstart + MCHUNK) : MM;
    const int p0     = blockIdx.x * 8;
    const int tid    = threadIdx.x;

    __shared__ float2 sA[8][KP];
    __shared__ float2 sB[8][KP];
    for (int idx = tid; idx < 8 * KP; idx += 128) {
        int pi = idx / KP, k = idx - pi * KP;
        size_t g = (size_t)(b * NP + p0 + pi) * KP + k;
        sA[pi][k] = A[g];
        sB[pi][k] = B[g];
    }
    __syncthreads();

    float2 bb[8];
    #pragma unroll
    for (int pi = 0; pi < 8; ++pi) bb[pi] = sB[pi][tid];

    float e0[8], e1[8];
    #pragma unroll
    for (int i = 0; i < 8; ++i) { e0[i] = 0.f; e1[i] = 0.f; }

    const float2* __restrict__ Sb = S + (size_t)b * KP * KP;
    float2 s = Sb[(size_t)mstart * KP + tid];
    float2 w = Wp[(size_t)mstart * KP + tid];
    for (int m = mstart; m < mend; ++m) {
        float2 sn = s, wn = w;
        if (m + 1 < mend) {
            sn = Sb[(size_t)(m + 1) * KP + tid];
            wn = Wp[(size_t)(m + 1) * KP + tid];
        }
        #pragma unroll
        for (int pi = 0; pi < 8; ++pi) {
            float2 a  = sA[pi][m];            // broadcast
            float2 bv = bb[pi];
            float abr = a.x * bv.x - a.y * bv.y;
            float abi = a.x * bv.y + a.y * bv.x;
            float d   = fmaf(s.x, abr, s.y * abi) - fmaf(abr, abr, abi * abi);
            e0[pi] = fmaf(w.x, d, e0[pi]);
            e1[pi] = fmaf(w.y, d, e1[pi]);
        }
        s = sn; w = wn;
    }
    // n = 128 column: thread tid handles m = mstart + tid
    if (tid < mend - mstart) {
        const int m = mstart + tid;
        float2 s8 = Sb[(size_t)m * KP + 128];
        float2 w8 = Wp[(size_t)m * KP + 128];
        #pragma unroll
        for (int pi = 0; pi < 8; ++pi) {
            float2 a  = sA[pi][m];
            float2 bv = sB[pi][128];
            float abr = a.x * bv.x - a.y * bv.y;
            float abi = a.x * bv.y + a.y * bv.x;
            float d   = fmaf(s8.x, abr, s8.y * abi) - fmaf(abr, abr, abi * abi);
            e0[pi] = fmaf(w8.x, d, e0[pi]);
            e1[pi] = fmaf(w8.y, d, e1[pi]);
        }
    }

    // reduce 128 threads -> 16 partials (8 points x 2 channels), atomic to out
    const int lane = tid & 63, wv = tid >> 6;
    __shared__ float part[2][16];
    #pragma unroll
    for (int pi = 0; pi < 8; ++pi) {
        float r0 = e0[pi], r1 = e1[pi];
        #pragma unroll
        for (int o = 32; o > 0; o >>= 1) {
            r0 += __shfl_down(r0, o, 64);
            r1 += __shfl_down(r1, o, 64);
        }
        if (lane == 0) { part[wv][pi * 2 + 0] = r0; part[wv][pi * 2 + 1] = r1; }
    }
    __syncthreads();
    if (tid < 16) {
        float r = part[0][tid] + part[1][tid];
        int pi = tid >> 1, c = tid & 1;
        atomicAdd(&out[((size_t)(b * NP + p0 + pi)) * 2 + c], r);
    }
}

// ---------------------------------------------------------------------------
extern "C" void kernel_launch(void* const* d_in, const int* in_sizes, int n_in,
                              void* d_out, int out_size, void* d_ws, size_t ws_size,
                              hipStream_t stream) {
    const float* x      = (const float*)d_in[0];
    const float* shift0 = (const float*)d_in[1];
    const float* shift1 = (const float*)d_in[2];
    const float* amp0   = (const float*)d_in[3];
    const float* amp1   = (const float*)d_in[4];
    float* out = (float*)d_out;

    // workspace layout (float2-aligned)
    float2* A  = (float2*)d_ws;                 // [NB][NP][KP]
    float2* Bv = A + (size_t)NB * NP * KP;      // [NB][NP][KP]
    float2* S  = Bv + (size_t)NB * NP * KP;     // [NB][KP][KP]
    float2* Wp = S + (size_t)NB * KP * KP;      // [KP*KP] packed (w0,w1)
    float2* Tw = Wp + (size_t)KP * KP;          // [MM*KP] twiddle table

    k_setup<<<(S_FLOATS + 255) / 256, 256, 0, stream>>>(shift0, shift1, amp0, amp1,
                                                        (float*)S, out, Tw, Wp);
    k_dft<<<(NB * NP) / PPB, 128, 0, stream>>>(x, Tw, A, Bv);
    k_s<<<dim3(KP / 4, NP / PCHUNK, NB), 128, 0, stream>>>(A, Bv, S);
    k_final<<<dim3(NP / 8, 8, NB), 128, 0, stream>>>(A, Bv, S, Wp, out);
}

// Round 6
// 126.532 us; speedup vs baseline: 1.2727x; 1.0138x over previous
//
#include <hip/hip_runtime.h>
#include <math.h>

// Problem constants (from reference)
#define MM 129      // mesh points per axis (odd)
#define KP 132      // padded K dim
#define NP 512      // points per batch
#define NB 4        // batches

static constexpr double D_PI  = 3.14159265358979323846;
static constexpr double D_L   = 2.0 * D_PI;
static constexpr double D_TAU = 12.0 / ((double)MM * (double)MM);
static constexpr double D_INV4TAU = 1.0 / (4.0 * D_TAU);
// scale/M^2 = 1/(8*pi^2*M^4) folded into W tables
static constexpr double D_F = 1.0 / (8.0 * D_PI * D_PI * (double)MM * (double)MM * (double)MM * (double)MM);

__device__ __forceinline__ void cmac(float2& acc, float2 a, float2 b) {
    acc.x = fmaf(a.x, b.x, fmaf(-a.y, b.y, acc.x));
    acc.y = fmaf(a.x, b.y, fmaf( a.y, b.x, acc.y));
}

// ---------------------------------------------------------------------------
// Kernel 0 (fused setup): zero S rows 0..67 + out; build Tw (129x132) and
// W rows 0..64 (only the parts later kernels read).
// ---------------------------------------------------------------------------
#define S_ZERO_PER_B (68 * KP * 2)
#define OUT_FLOATS (NB * NP * 2)
__global__ __launch_bounds__(256) void k_setup(const float* __restrict__ s0p,
                                               const float* __restrict__ s1p,
                                               const float* __restrict__ a0p,
                                               const float* __restrict__ a1p,
                                               float* __restrict__ S,
                                               float* __restrict__ out,
                                               float2* __restrict__ Tw,
                                               float2* __restrict__ Wp) {
    const int i = blockIdx.x * 256 + threadIdx.x;
    const int stride = gridDim.x * 256;
    for (int j = i; j < NB * S_ZERO_PER_B; j += stride) {
        int b = j / S_ZERO_PER_B, r = j - b * S_ZERO_PER_B;
        S[(size_t)b * KP * KP * 2 + r] = 0.f;
    }
    for (int j = i; j < OUT_FLOATS; j += stride) out[j] = 0.f;
    for (int j = i; j < MM * KP; j += stride) {
        int a = j / KP, k = j - (j / KP) * KP;
        float2 v = make_float2(0.f, 0.f);
        if (k < MM) {
            int kcm = k - 64; if (kcm < 0) kcm += MM;
            int ph  = (kcm * a) % MM;
            float th = (float)(-2.0 * D_PI / MM) * (float)ph;
            float s, c;
            __sincosf(th, &s, &c);
            v = make_float2(c, s);
        }
        Tw[j] = v;
    }
    for (int j = i; j < 65 * KP; j += stride) {   // rows m = 0..64 only
        int m = j / KP, n = j - (j / KP) * KP;
        float w0 = 0.f, w1 = 0.f;
        if (n < MM) {
            float kx = (float)(m - 64), ky = (float)(n - 64);
            float k2   = kx * kx + ky * ky;
            float dec  = (float)(D_PI / D_TAU) * expf(k2 * (float)D_TAU);
            float base = dec * dec * (float)(4.0 * D_PI * D_F);
            float s0 = s0p[0], s1 = s1p[0];   // mu0 = mu1 = 1
            w0 = a0p[0] * base / (k2 + s0 * s0);
            w1 = a1p[0] * base / (k2 + s1 * s1);
        }
        Wp[j] = make_float2(w0, w1);
    }
}

// ---------------------------------------------------------------------------
// Kernel 1: per-point Gaussian sampling + DFT for k = 64..127 only (Hermitian:
// A[64-j] = conj(A[64+j])); k=128 via block reduce, k=0 = conj(k=128).
// 2 points/block, 1024 blocks x 128 threads; lane = (pt = tid&1, j = tid>>1).
// Inner loop: 1x 8B Tw load (2-lane dup), 1 near-broadcast LDS b64, 4 FMA.
// ---------------------------------------------------------------------------
#define PPB 2
__global__ __launch_bounds__(128) void k_dft(const float* __restrict__ x,
                                             const float2* __restrict__ Tw,
                                             float2* __restrict__ A,
                                             float2* __restrict__ B) {
    const int p0  = blockIdx.x * PPB;    // global point index (b*NP+p)
    const int tid = threadIdx.x;

    __shared__ float4 sG[MM];            // (ga_p0, gb_p0, ga_p1, gb_p1)
    __shared__ float red[2][8];

    const float inv4tau = (float)D_INV4TAU;
    const float Lf      = (float)D_L;
    for (int idx = tid; idx < MM * PPB; idx += 128) {
        int pt = idx & 1, a = idx >> 1;
        float x0 = x[(p0 + pt) * 2 + 0];
        float x1 = x[(p0 + pt) * 2 + 1];
        float u  = (float)a * (float)(D_L / MM);
        float d0 = x0 - u, d1 = x1 - u;
        float ga = expf(-d0 * d0 * inv4tau)
                 + expf(-(d0 - Lf) * (d0 - Lf) * inv4tau)
                 + expf(-(d0 + Lf) * (d0 + Lf) * inv4tau);
        float gb = expf(-d1 * d1 * inv4tau)
                 + expf(-(d1 - Lf) * (d1 - Lf) * inv4tau)
                 + expf(-(d1 + Lf) * (d1 + Lf) * inv4tau);
        ((float2*)&sG[a])[pt] = make_float2(ga, gb);
    }
    __syncthreads();

    const int pt = tid & 1;
    const int j  = tid >> 1;             // 0..63 -> k = 64+j
    const int kk = 64 + j;

    float Ar = 0.f, Ai = 0.f, Br = 0.f, Bi = 0.f;
    #pragma unroll 4
    for (int a = 0; a < MM; ++a) {
        float2 t = Tw[a * KP + kk];                    // L2-resident
        float2 g = ((const float2*)&sG[a])[pt];        // 2 distinct addrs/wave
        Ar = fmaf(g.x, t.x, Ar); Ai = fmaf(g.x, t.y, Ai);
        Br = fmaf(g.y, t.x, Br); Bi = fmaf(g.y, t.y, Bi);
    }

    {
        const size_t base = (size_t)(p0 + pt) * KP;
        A[base + kk] = make_float2(Ar, Ai);
        B[base + kk] = make_float2(Br, Bi);
        if (j > 0) {                                    // Hermitian mirror
            A[base + 64 - j] = make_float2(Ar, -Ai);
            B[base + 64 - j] = make_float2(Br, -Bi);
        }
    }

    // ----- k = 128 (kc=+64): reduce over a across the block; k=0 = conj -----
    const int lane = tid & 63, wv = tid >> 6;
    float2 t1   = Tw[tid * KP + 128];   // a = tid
    float2 t128 = Tw[128 * KP + 128];
    float4 gt   = sG[tid];
    float4 g128 = sG[128];
    #pragma unroll
    for (int p = 0; p < PPB; ++p) {
        float ga = p ? gt.z : gt.x;
        float gb = p ? gt.w : gt.y;
        float ar = ga * t1.x, ai = ga * t1.y;
        float br = gb * t1.x, bi = gb * t1.y;
        if (tid == 0) {   // a = 128 term
            float ga8 = p ? g128.z : g128.x;
            float gb8 = p ? g128.w : g128.y;
            ar = fmaf(ga8, t128.x, ar); ai = fmaf(ga8, t128.y, ai);
            br = fmaf(gb8, t128.x, br); bi = fmaf(gb8, t128.y, bi);
        }
        #pragma unroll
        for (int o = 32; o > 0; o >>= 1) {
            ar += __shfl_down(ar, o, 64); ai += __shfl_down(ai, o, 64);
            br += __shfl_down(br, o, 64); bi += __shfl_down(bi, o, 64);
        }
        if (lane == 0) {
            red[wv][p * 4 + 0] = ar; red[wv][p * 4 + 1] = ai;
            red[wv][p * 4 + 2] = br; red[wv][p * 4 + 3] = bi;
        }
    }
    __syncthreads();
    if (tid < 4) {
        int p = tid >> 1, isB = tid & 1;
        float re = red[0][p * 4 + isB * 2 + 0] + red[1][p * 4 + isB * 2 + 0];
        float im = red[0][p * 4 + isB * 2 + 1] + red[1][p * 4 + isB * 2 + 1];
        float2* dst = isB ? B : A;
        const size_t base = (size_t)(p0 + p) * KP;
        dst[base + 128] = make_float2(re, im);
        dst[base + 0]   = make_float2(re, -im);
    }
}

// ---------------------------------------------------------------------------
// Kernel 3: S_b[m,n] += sum_p A[b,p,m]*B[b,p,n], rows m = 0..67 only
// (k_final reads m <= 64; S[128-m,128-n] = conj(S[m,n]) never materialized).
// Grid: (17 m-tiles, 32 p-chunks, 4 batches) = 2176 blocks, 128 threads.
// ---------------------------------------------------------------------------
#define PCHUNK 16
__global__ __launch_bounds__(128) void k_s(const float2* __restrict__ A,
                                           const float2* __restrict__ B,
                                           float2* __restrict__ S) {
    const int b   = blockIdx.z;
    const int p0  = blockIdx.y * PCHUNK;
    const int m0  = blockIdx.x * 4;       // 0..64
    const int tid = threadIdx.x;

    const float2* __restrict__ Ab = A + (size_t)b * NP * KP;
    const float2* __restrict__ Bb = B + (size_t)b * NP * KP;

    float2 acc[4];
    #pragma unroll
    for (int i = 0; i < 4; ++i) acc[i] = make_float2(0.f, 0.f);
    float2 acc2 = make_float2(0.f, 0.f);   // S[m0+tid][128], lanes 0..3

    float2 v[4], am[4][4], as[4], bu[4];
    #pragma unroll
    for (int i = 0; i < 4; ++i) {
        const size_t r = (size_t)(p0 + i) * KP;
        v[i]  = Bb[r + tid];
        bu[i] = Bb[r + 128];                 // wave-uniform
        as[i] = Ab[r + m0 + (tid & 3)];      // per-lane A for the n=128 path
        #pragma unroll
        for (int j = 0; j < 4; ++j) am[i][j] = Ab[r + m0 + j];   // wave-uniform
    }

    for (int pg = 0; pg < PCHUNK; pg += 4) {
        float2 nv[4], nam[4][4], nas[4], nbu[4];
        const bool more = (pg + 4 < PCHUNK);
        if (more) {
            #pragma unroll
            for (int i = 0; i < 4; ++i) {
                const size_t r = (size_t)(p0 + pg + 4 + i) * KP;
                nv[i]  = Bb[r + tid];
                nbu[i] = Bb[r + 128];
                nas[i] = Ab[r + m0 + (tid & 3)];
                #pragma unroll
                for (int j = 0; j < 4; ++j) nam[i][j] = Ab[r + m0 + j];
            }
        }
        #pragma unroll
        for (int i = 0; i < 4; ++i) {
            cmac(acc[0], am[i][0], v[i]);
            cmac(acc[1], am[i][1], v[i]);
            cmac(acc[2], am[i][2], v[i]);
            cmac(acc[3], am[i][3], v[i]);
        }
        if (tid < 4) {
            #pragma unroll
            for (int i = 0; i < 4; ++i) cmac(acc2, as[i], bu[i]);
        }
        if (more) {
            #pragma unroll
            for (int i = 0; i < 4; ++i) {
                v[i] = nv[i]; bu[i] = nbu[i]; as[i] = nas[i];
                #pragma unroll
                for (int j = 0; j < 4; ++j) am[i][j] = nam[i][j];
            }
        }
    }

    float* Sb = (float*)(S + (size_t)b * KP * KP);
    #pragma unroll
    for (int i = 0; i < 4; ++i) {
        atomicAdd(&Sb[((size_t)(m0 + i) * KP + tid) * 2 + 0], acc[i].x);
        atomicAdd(&Sb[((size_t)(m0 + i) * KP + tid) * 2 + 1], acc[i].y);
    }
    if (tid < 4) {
        atomicAdd(&Sb[((size_t)(m0 + tid) * KP + 128) * 2 + 0], acc2.x);
        atomicAdd(&Sb[((size_t)(m0 + tid) * KP + 128) * 2 + 1], acc2.y);
    }
}

// ---------------------------------------------------------------------------
// Kernel 4: per point p (8 per block), both channels. Mirror symmetry:
//   full sum = 2*sum_{m<64, all n} + 2*sum_{m=64, n<64} + (m=64,n=64).
// Grid: (64 point-groups, 8 m-chunks of 8 rows, 4 batches) = 2048 blocks.
// Chunk mc covers m = 8mc..8mc+7 (weight 2, folded as final x2);
// mc==7 additionally handles the m=64 row with per-lane weights.
// ---------------------------------------------------------------------------
__global__ __launch_bounds__(128) void k_final(const float2* __restrict__ A,
                                               const float2* __restrict__ B,
                                               const float2* __restrict__ S,
                                               const float2* __restrict__ Wp,
                                               float* __restrict__ out) {
    const int b      = blockIdx.z;
    const int mc     = blockIdx.y;
    const int mstart = mc * 8;           // rows mstart..mstart+7 (<= 63)
    const int p0     = blockIdx.x * 8;
    const int tid    = threadIdx.x;

    __shared__ float2 sA[8][65];         // k = 0..64 (only m<=64 read)
    __shared__ float2 sB[8][KP];         // k = 0..128 used
    for (int idx = tid; idx < 8 * 65; idx += 128) {
        int pi = idx / 65, k = idx - pi * 65;
        sA[pi][k] = A[(size_t)(b * NP + p0 + pi) * KP + k];
    }
    for (int idx = tid; idx < 8 * 129; idx += 128) {
        int pi = idx / 129, k = idx - pi * 129;
        sB[pi][k] = B[(size_t)(b * NP + p0 + pi) * KP + k];
    }
    __syncthreads();

    float2 bb[8];
    #pragma unroll
    for (int pi = 0; pi < 8; ++pi) bb[pi] = sB[pi][tid];

    float e0[8], e1[8];
    #pragma unroll
    for (int i = 0; i < 8; ++i) { e0[i] = 0.f; e1[i] = 0.f; }

    const float2* __restrict__ Sb = S + (size_t)b * KP * KP;
    float2 s = Sb[(size_t)mstart * KP + tid];
    float2 w = Wp[(size_t)mstart * KP + tid];
    #pragma unroll
    for (int mi = 0; mi < 8; ++mi) {
        const int m = mstart + mi;
        float2 sn = s, wn = w;
        if (mi < 7) {
            sn = Sb[(size_t)(m + 1) * KP + tid];
            wn = Wp[(size_t)(m + 1) * KP + tid];
        }
        #pragma unroll
        for (int pi = 0; pi < 8; ++pi) {
            float2 a  = sA[pi][m];            // broadcast
            float2 bv = bb[pi];
            float abr = a.x * bv.x - a.y * bv.y;
            float abi = a.x * bv.y + a.y * bv.x;
            float d   = fmaf(s.x, abr, s.y * abi) - fmaf(abr, abr, abi * abi);
            e0[pi] = fmaf(w.x, d, e0[pi]);
            e1[pi] = fmaf(w.y, d, e1[pi]);
        }
        s = sn; w = wn;
    }
    // n = 128 column for this chunk's rows (all m <= 63, weight 2 via fold)
    if (tid < 8) {
        const int m = mstart + tid;
        float2 s8 = Sb[(size_t)m * KP + 128];
        float2 w8 = Wp[(size_t)m * KP + 128];
        #pragma unroll
        for (int pi = 0; pi < 8; ++pi) {
            float2 a  = sA[pi][m];
            float2 bv = sB[pi][128];
            float abr = a.x * bv.x - a.y * bv.y;
            float abi = a.x * bv.y + a.y * bv.x;
            float d   = fmaf(s8.x, abr, s8.y * abi) - fmaf(abr, abr, abi * abi);
            e0[pi] = fmaf(w8.x, d, e0[pi]);
            e1[pi] = fmaf(w8.y, d, e1[pi]);
        }
    }
    // fold the mirror weight (x2) for all m < 64 contributions
    #pragma unroll
    for (int i = 0; i < 8; ++i) { e0[i] *= 2.f; e1[i] *= 2.f; }

    // mc==7: the self-mirror row m=64: n<64 weight 2, n=64 weight 1, n>64 none
    if (mc == 7) {
        float wt = (tid < 64) ? 2.f : ((tid == 64) ? 1.f : 0.f);
        float2 s64 = Sb[(size_t)64 * KP + tid];
        float2 w64 = Wp[(size_t)64 * KP + tid];
        w64.x *= wt; w64.y *= wt;
        #pragma unroll
        for (int pi = 0; pi < 8; ++pi) {
            float2 a  = sA[pi][64];
            float2 bv = bb[pi];
            float abr = a.x * bv.x - a.y * bv.y;
            float abi = a.x * bv.y + a.y * bv.x;
            float d   = fmaf(s64.x, abr, s64.y * abi) - fmaf(abr, abr, abi * abi);
            e0[pi] = fmaf(w64.x, d, e0[pi]);
            e1[pi] = fmaf(w64.y, d, e1[pi]);
        }
    }

    // reduce 128 threads -> 16 partials (8 points x 2 channels), atomic to out
    const int lane = tid & 63, wv = tid >> 6;
    __shared__ float part[2][16];
    #pragma unroll
    for (int pi = 0; pi < 8; ++pi) {
        float r0 = e0[pi], r1 = e1[pi];
        #pragma unroll
        for (int o = 32; o > 0; o >>= 1) {
            r0 += __shfl_down(r0, o, 64);
            r1 += __shfl_down(r1, o, 64);
        }
        if (lane == 0) { part[wv][pi * 2 + 0] = r0; part[wv][pi * 2 + 1] = r1; }
    }
    __syncthreads();
    if (tid < 16) {
        float r = part[0][tid] + part[1][tid];
        int pi = tid >> 1, c = tid & 1;
        atomicAdd(&out[((size_t)(b * NP + p0 + pi)) * 2 + c], r);
    }
}

// ---------------------------------------------------------------------------
extern "C" void kernel_launch(void* const* d_in, const int* in_sizes, int n_in,
                              void* d_out, int out_size, void* d_ws, size_t ws_size,
                              hipStream_t stream) {
    const float* x      = (const float*)d_in[0];
    const float* shift0 = (const float*)d_in[1];
    const float* shift1 = (const float*)d_in[2];
    const float* amp0   = (const float*)d_in[3];
    const float* amp1   = (const float*)d_in[4];
    float* out = (float*)d_out;

    // workspace layout (float2-aligned)
    float2* A  = (float2*)d_ws;                 // [NB][NP][KP]
    float2* Bv = A + (size_t)NB * NP * KP;      // [NB][NP][KP]
    float2* S  = Bv + (size_t)NB * NP * KP;     // [NB][KP][KP]
    float2* Wp = S + (size_t)NB * KP * KP;      // [65*KP] packed (w0,w1)
    float2* Tw = Wp + (size_t)65 * KP;          // [MM*KP] twiddle table

    k_setup<<<256, 256, 0, stream>>>(shift0, shift1, amp0, amp1,
                                     (float*)S, out, Tw, Wp);
    k_dft<<<(NB * NP) / PPB, 128, 0, stream>>>(x, Tw, A, Bv);
    k_s<<<dim3(17, NP / PCHUNK, NB), 128, 0, stream>>>(A, Bv, S);
    k_final<<<dim3(NP / 8, 8, NB), 128, 0, stream>>>(A, Bv, S, Wp, out);
}

// Round 7
// 117.106 us; speedup vs baseline: 1.3751x; 1.0805x over previous
//
#include <hip/hip_runtime.h>
#include <math.h>

// Problem constants (from reference)
#define MM 129      // mesh points per axis (odd)
#define KP 132      // padded K dim
#define NP 512      // points per batch
#define NB 4        // batches
#define NPC 16      // p-chunks for the two-stage S reduction
#define PCHUNK (NP / NPC)

static constexpr double D_PI  = 3.14159265358979323846;
static constexpr double D_L   = 2.0 * D_PI;
static constexpr double D_TAU = 12.0 / ((double)MM * (double)MM);
static constexpr double D_INV4TAU = 1.0 / (4.0 * D_TAU);
// scale/M^2 = 1/(8*pi^2*M^4) folded into W tables
static constexpr double D_F = 1.0 / (8.0 * D_PI * D_PI * (double)MM * (double)MM * (double)MM * (double)MM);

__device__ __forceinline__ void cmac(float2& acc, float2 a, float2 b) {
    acc.x = fmaf(a.x, b.x, fmaf(-a.y, b.y, acc.x));
    acc.y = fmaf(a.x, b.y, fmaf( a.y, b.x, acc.y));
}

// ---------------------------------------------------------------------------
// Kernel 0 (fused setup): zero out; build Tw (129x132) and W rows 0..64.
// (S is no longer zeroed: k_s2 overwrites it.)
// ---------------------------------------------------------------------------
#define OUT_FLOATS (NB * NP * 2)
__global__ __launch_bounds__(256) void k_setup(const float* __restrict__ s0p,
                                               const float* __restrict__ s1p,
                                               const float* __restrict__ a0p,
                                               const float* __restrict__ a1p,
                                               float* __restrict__ out,
                                               float2* __restrict__ Tw,
                                               float2* __restrict__ Wp) {
    const int i = blockIdx.x * 256 + threadIdx.x;
    const int stride = gridDim.x * 256;
    for (int j = i; j < OUT_FLOATS; j += stride) out[j] = 0.f;
    for (int j = i; j < MM * KP; j += stride) {
        int a = j / KP, k = j - (j / KP) * KP;
        float2 v = make_float2(0.f, 0.f);
        if (k < MM) {
            int kcm = k - 64; if (kcm < 0) kcm += MM;
            int ph  = (kcm * a) % MM;
            float th = (float)(-2.0 * D_PI / MM) * (float)ph;
            float s, c;
            __sincosf(th, &s, &c);
            v = make_float2(c, s);
        }
        Tw[j] = v;
    }
    for (int j = i; j < 65 * KP; j += stride) {   // rows m = 0..64 only
        int m = j / KP, n = j - (j / KP) * KP;
        float w0 = 0.f, w1 = 0.f;
        if (n < MM) {
            float kx = (float)(m - 64), ky = (float)(n - 64);
            float k2   = kx * kx + ky * ky;
            float dec  = (float)(D_PI / D_TAU) * expf(k2 * (float)D_TAU);
            float base = dec * dec * (float)(4.0 * D_PI * D_F);
            float s0 = s0p[0], s1 = s1p[0];   // mu0 = mu1 = 1
            w0 = a0p[0] * base / (k2 + s0 * s0);
            w1 = a1p[0] * base / (k2 + s1 * s1);
        }
        Wp[j] = make_float2(w0, w1);
    }
}

// ---------------------------------------------------------------------------
// Kernel 1: per-point Gaussian sampling + DFT for k = 64..127 only (Hermitian:
// A[64-j] = conj(A[64+j])); k=128 via block reduce, k=0 = conj(k=128).
// 2 points/block, 1024 blocks x 128 threads; lane = (pt = tid&1, j = tid>>1).
// ---------------------------------------------------------------------------
#define PPB 2
__global__ __launch_bounds__(128) void k_dft(const float* __restrict__ x,
                                             const float2* __restrict__ Tw,
                                             float2* __restrict__ A,
                                             float2* __restrict__ B) {
    const int p0  = blockIdx.x * PPB;    // global point index (b*512+p)
    const int tid = threadIdx.x;

    __shared__ float4 sG[MM];            // (ga_p0, gb_p0, ga_p1, gb_p1)
    __shared__ float red[2][8];

    const float inv4tau = (float)D_INV4TAU;
    const float Lf      = (float)D_L;
    for (int idx = tid; idx < MM * PPB; idx += 128) {
        int pt = idx & 1, a = idx >> 1;
        float x0 = x[(p0 + pt) * 2 + 0];
        float x1 = x[(p0 + pt) * 2 + 1];
        float u  = (float)a * (float)(D_L / MM);
        float d0 = x0 - u, d1 = x1 - u;
        float ga = expf(-d0 * d0 * inv4tau)
                 + expf(-(d0 - Lf) * (d0 - Lf) * inv4tau)
                 + expf(-(d0 + Lf) * (d0 + Lf) * inv4tau);
        float gb = expf(-d1 * d1 * inv4tau)
                 + expf(-(d1 - Lf) * (d1 - Lf) * inv4tau)
                 + expf(-(d1 + Lf) * (d1 + Lf) * inv4tau);
        ((float2*)&sG[a])[pt] = make_float2(ga, gb);
    }
    __syncthreads();

    const int pt = tid & 1;
    const int j  = tid >> 1;             // 0..63 -> k = 64+j
    const int kk = 64 + j;

    float Ar = 0.f, Ai = 0.f, Br = 0.f, Bi = 0.f;
    #pragma unroll 4
    for (int a = 0; a < MM; ++a) {
        float2 t = Tw[a * KP + kk];                    // L2-resident
        float2 g = ((const float2*)&sG[a])[pt];        // 2 distinct addrs/wave
        Ar = fmaf(g.x, t.x, Ar); Ai = fmaf(g.x, t.y, Ai);
        Br = fmaf(g.y, t.x, Br); Bi = fmaf(g.y, t.y, Bi);
    }

    {
        const size_t base = (size_t)(p0 + pt) * KP;
        A[base + kk] = make_float2(Ar, Ai);
        B[base + kk] = make_float2(Br, Bi);
        if (j > 0) {                                    // Hermitian mirror
            A[base + 64 - j] = make_float2(Ar, -Ai);
            B[base + 64 - j] = make_float2(Br, -Bi);
        }
    }

    // ----- k = 128 (kc=+64): reduce over a across the block; k=0 = conj -----
    const int lane = tid & 63, wv = tid >> 6;
    float2 t1   = Tw[tid * KP + 128];   // a = tid
    float2 t128 = Tw[128 * KP + 128];
    float4 gt   = sG[tid];
    float4 g128 = sG[128];
    #pragma unroll
    for (int p = 0; p < PPB; ++p) {
        float ga = p ? gt.z : gt.x;
        float gb = p ? gt.w : gt.y;
        float ar = ga * t1.x, ai = ga * t1.y;
        float br = gb * t1.x, bi = gb * t1.y;
        if (tid == 0) {   // a = 128 term
            float ga8 = p ? g128.z : g128.x;
            float gb8 = p ? g128.w : g128.y;
            ar = fmaf(ga8, t128.x, ar); ai = fmaf(ga8, t128.y, ai);
            br = fmaf(gb8, t128.x, br); bi = fmaf(gb8, t128.y, bi);
        }
        #pragma unroll
        for (int o = 32; o > 0; o >>= 1) {
            ar += __shfl_down(ar, o, 64); ai += __shfl_down(ai, o, 64);
            br += __shfl_down(br, o, 64); bi += __shfl_down(bi, o, 64);
        }
        if (lane == 0) {
            red[wv][p * 4 + 0] = ar; red[wv][p * 4 + 1] = ai;
            red[wv][p * 4 + 2] = br; red[wv][p * 4 + 3] = bi;
        }
    }
    __syncthreads();
    if (tid < 4) {
        int p = tid >> 1, isB = tid & 1;
        float re = red[0][p * 4 + isB * 2 + 0] + red[1][p * 4 + isB * 2 + 0];
        float im = red[0][p * 4 + isB * 2 + 1] + red[1][p * 4 + isB * 2 + 1];
        float2* dst = isB ? B : A;
        const size_t base = (size_t)(p0 + p) * KP;
        dst[base + 128] = make_float2(re, im);
        dst[base + 0]   = make_float2(re, -im);
    }
}

// ---------------------------------------------------------------------------
// Kernel 2a: stage-1 of S: partial outer products, NO atomics.
// P[b][pc][m(0..67)][n] = sum_{p in chunk pc} A[b,p,m]*B[b,p,n]
// Grid: (17 m-tiles, 16 p-chunks, 4 batches) = 1088 blocks, 128 threads.
// ---------------------------------------------------------------------------
__global__ __launch_bounds__(128) void k_s1(const float2* __restrict__ A,
                                            const float2* __restrict__ B,
                                            float2* __restrict__ P) {
    const int b   = blockIdx.z;
    const int pc  = blockIdx.y;
    const int p0  = pc * PCHUNK;
    const int m0  = blockIdx.x * 4;       // 0..64
    const int tid = threadIdx.x;

    const float2* __restrict__ Ab = A + (size_t)b * NP * KP;
    const float2* __restrict__ Bb = B + (size_t)b * NP * KP;

    float2 acc[4];
    #pragma unroll
    for (int i = 0; i < 4; ++i) acc[i] = make_float2(0.f, 0.f);
    float2 acc2 = make_float2(0.f, 0.f);   // P[m0+lane][128], lanes 0..3

    float2 v[4], am[4][4], as[4], bu[4];
    #pragma unroll
    for (int i = 0; i < 4; ++i) {
        const size_t r = (size_t)(p0 + i) * KP;
        v[i]  = Bb[r + tid];
        bu[i] = Bb[r + 128];                 // wave-uniform
        as[i] = Ab[r + m0 + (tid & 3)];      // per-lane A for the n=128 path
        #pragma unroll
        for (int j = 0; j < 4; ++j) am[i][j] = Ab[r + m0 + j];   // wave-uniform
    }

    for (int pg = 0; pg < PCHUNK; pg += 4) {
        float2 nv[4], nam[4][4], nas[4], nbu[4];
        const bool more = (pg + 4 < PCHUNK);
        if (more) {
            #pragma unroll
            for (int i = 0; i < 4; ++i) {
                const size_t r = (size_t)(p0 + pg + 4 + i) * KP;
                nv[i]  = Bb[r + tid];
                nbu[i] = Bb[r + 128];
                nas[i] = Ab[r + m0 + (tid & 3)];
                #pragma unroll
                for (int j = 0; j < 4; ++j) nam[i][j] = Ab[r + m0 + j];
            }
        }
        #pragma unroll
        for (int i = 0; i < 4; ++i) {
            cmac(acc[0], am[i][0], v[i]);
            cmac(acc[1], am[i][1], v[i]);
            cmac(acc[2], am[i][2], v[i]);
            cmac(acc[3], am[i][3], v[i]);
        }
        if (tid < 4) {
            #pragma unroll
            for (int i = 0; i < 4; ++i) cmac(acc2, as[i], bu[i]);
        }
        if (more) {
            #pragma unroll
            for (int i = 0; i < 4; ++i) {
                v[i] = nv[i]; bu[i] = nbu[i]; as[i] = nas[i];
                #pragma unroll
                for (int j = 0; j < 4; ++j) am[i][j] = nam[i][j];
            }
        }
    }

    float2* Pb = P + ((size_t)(b * NPC + pc) * 68) * KP;
    #pragma unroll
    for (int i = 0; i < 4; ++i)
        Pb[(size_t)(m0 + i) * KP + tid] = acc[i];      // coalesced store
    if (tid < 4)
        Pb[(size_t)(m0 + tid) * KP + 128] = acc2;
}

// ---------------------------------------------------------------------------
// Kernel 2b: stage-2: S[b][m][n] = sum_{pc} P[b][pc][m][n], n <= 128.
// 4*68*132 index space, 256-thread blocks; 16 independent pipelined loads/thread.
// ---------------------------------------------------------------------------
__global__ __launch_bounds__(256) void k_s2(const float2* __restrict__ P,
                                            float2* __restrict__ S) {
    const int idx = blockIdx.x * 256 + threadIdx.x;
    if (idx >= NB * 68 * KP) return;
    const int b   = idx / (68 * KP);
    const int rem = idx - b * (68 * KP);
    const int m   = rem / KP;
    const int n   = rem - m * KP;
    if (n > 128) return;                  // cols 129..131 never written/read

    const float2* __restrict__ Pb = P + ((size_t)b * NPC * 68) * KP + (size_t)m * KP + n;
    float re = 0.f, im = 0.f;
    #pragma unroll
    for (int pc = 0; pc < NPC; ++pc) {
        float2 v = Pb[(size_t)pc * 68 * KP];
        re += v.x; im += v.y;
    }
    S[(size_t)b * KP * KP + (size_t)m * KP + n] = make_float2(re, im);
}

// ---------------------------------------------------------------------------
// Kernel 3: per point p (8 per block), both channels. Mirror symmetry:
//   full sum = 2*sum_{m<64, all n} + 2*sum_{m=64, n<64} + (m=64,n=64).
// Grid: (64 point-groups, 8 m-chunks of 8 rows, 4 batches) = 2048 blocks.
// ---------------------------------------------------------------------------
__global__ __launch_bounds__(128) void k_final(const float2* __restrict__ A,
                                               const float2* __restrict__ B,
                                               const float2* __restrict__ S,
                                               const float2* __restrict__ Wp,
                                               float* __restrict__ out) {
    const int b      = blockIdx.z;
    const int mc     = blockIdx.y;
    const int mstart = mc * 8;           // rows mstart..mstart+7 (<= 63)
    const int p0     = blockIdx.x * 8;
    const int tid    = threadIdx.x;

    __shared__ float2 sA[8][65];         // k = 0..64 (only m<=64 read)
    __shared__ float2 sB[8][KP];         // k = 0..128 used
    for (int idx = tid; idx < 8 * 65; idx += 128) {
        int pi = idx / 65, k = idx - pi * 65;
        sA[pi][k] = A[(size_t)(b * NP + p0 + pi) * KP + k];
    }
    for (int idx = tid; idx < 8 * 129; idx += 128) {
        int pi = idx / 129, k = idx - pi * 129;
        sB[pi][k] = B[(size_t)(b * NP + p0 + pi) * KP + k];
    }
    __syncthreads();

    float2 bb[8];
    #pragma unroll
    for (int pi = 0; pi < 8; ++pi) bb[pi] = sB[pi][tid];

    float e0[8], e1[8];
    #pragma unroll
    for (int i = 0; i < 8; ++i) { e0[i] = 0.f; e1[i] = 0.f; }

    const float2* __restrict__ Sb = S + (size_t)b * KP * KP;
    float2 s = Sb[(size_t)mstart * KP + tid];
    float2 w = Wp[(size_t)mstart * KP + tid];
    #pragma unroll
    for (int mi = 0; mi < 8; ++mi) {
        const int m = mstart + mi;
        float2 sn = s, wn = w;
        if (mi < 7) {
            sn = Sb[(size_t)(m + 1) * KP + tid];
            wn = Wp[(size_t)(m + 1) * KP + tid];
        }
        #pragma unroll
        for (int pi = 0; pi < 8; ++pi) {
            float2 a  = sA[pi][m];            // broadcast
            float2 bv = bb[pi];
            float abr = a.x * bv.x - a.y * bv.y;
            float abi = a.x * bv.y + a.y * bv.x;
            float d   = fmaf(s.x, abr, s.y * abi) - fmaf(abr, abr, abi * abi);
            e0[pi] = fmaf(w.x, d, e0[pi]);
            e1[pi] = fmaf(w.y, d, e1[pi]);
        }
        s = sn; w = wn;
    }
    // n = 128 column for this chunk's rows (all m <= 63, weight 2 via fold)
    if (tid < 8) {
        const int m = mstart + tid;
        float2 s8 = Sb[(size_t)m * KP + 128];
        float2 w8 = Wp[(size_t)m * KP + 128];
        #pragma unroll
        for (int pi = 0; pi < 8; ++pi) {
            float2 a  = sA[pi][m];
            float2 bv = sB[pi][128];
            float abr = a.x * bv.x - a.y * bv.y;
            float abi = a.x * bv.y + a.y * bv.x;
            float d   = fmaf(s8.x, abr, s8.y * abi) - fmaf(abr, abr, abi * abi);
            e0[pi] = fmaf(w8.x, d, e0[pi]);
            e1[pi] = fmaf(w8.y, d, e1[pi]);
        }
    }
    // fold the mirror weight (x2) for all m < 64 contributions
    #pragma unroll
    for (int i = 0; i < 8; ++i) { e0[i] *= 2.f; e1[i] *= 2.f; }

    // mc==7: the self-mirror row m=64: n<64 weight 2, n=64 weight 1, n>64 none
    if (mc == 7) {
        float wt = (tid < 64) ? 2.f : ((tid == 64) ? 1.f : 0.f);
        float2 s64 = Sb[(size_t)64 * KP + tid];
        float2 w64 = Wp[(size_t)64 * KP + tid];
        w64.x *= wt; w64.y *= wt;
        #pragma unroll
        for (int pi = 0; pi < 8; ++pi) {
            float2 a  = sA[pi][64];
            float2 bv = bb[pi];
            float abr = a.x * bv.x - a.y * bv.y;
            float abi = a.x * bv.y + a.y * bv.x;
            float d   = fmaf(s64.x, abr, s64.y * abi) - fmaf(abr, abr, abi * abi);
            e0[pi] = fmaf(w64.x, d, e0[pi]);
            e1[pi] = fmaf(w64.y, d, e1[pi]);
        }
    }

    // reduce 128 threads -> 16 partials (8 points x 2 channels), atomic to out
    const int lane = tid & 63, wv = tid >> 6;
    __shared__ float part[2][16];
    #pragma unroll
    for (int pi = 0; pi < 8; ++pi) {
        float r0 = e0[pi], r1 = e1[pi];
        #pragma unroll
        for (int o = 32; o > 0; o >>= 1) {
            r0 += __shfl_down(r0, o, 64);
            r1 += __shfl_down(r1, o, 64);
        }
        if (lane == 0) { part[wv][pi * 2 + 0] = r0; part[wv][pi * 2 + 1] = r1; }
    }
    __syncthreads();
    if (tid < 16) {
        float r = part[0][tid] + part[1][tid];
        int pi = tid >> 1, c = tid & 1;
        atomicAdd(&out[((size_t)(b * NP + p0 + pi)) * 2 + c], r);
    }
}

// ---------------------------------------------------------------------------
extern "C" void kernel_launch(void* const* d_in, const int* in_sizes, int n_in,
                              void* d_out, int out_size, void* d_ws, size_t ws_size,
                              hipStream_t stream) {
    const float* x      = (const float*)d_in[0];
    const float* shift0 = (const float*)d_in[1];
    const float* shift1 = (const float*)d_in[2];
    const float* amp0   = (const float*)d_in[3];
    const float* amp1   = (const float*)d_in[4];
    float* out = (float*)d_out;

    // workspace layout (float2-aligned)
    float2* A  = (float2*)d_ws;                 // [NB][NP][KP]
    float2* Bv = A + (size_t)NB * NP * KP;      // [NB][NP][KP]
    float2* S  = Bv + (size_t)NB * NP * KP;     // [NB][KP][KP]
    float2* Wp = S + (size_t)NB * KP * KP;      // [65*KP] packed (w0,w1)
    float2* Tw = Wp + (size_t)65 * KP;          // [MM*KP] twiddle table
    float2* P  = Tw + (size_t)MM * KP;          // [NB*NPC][68][KP] partials (~4.6 MB)

    k_setup<<<256, 256, 0, stream>>>(shift0, shift1, amp0, amp1, out, Tw, Wp);
    k_dft<<<(NB * NP) / PPB, 128, 0, stream>>>(x, Tw, A, Bv);
    k_s1<<<dim3(17, NPC, NB), 128, 0, stream>>>(A, Bv, P);
    k_s2<<<(NB * 68 * KP + 255) / 256, 256, 0, stream>>>(P, S);
    k_final<<<dim3(NP / 8, 8, NB), 128, 0, stream>>>(A, Bv, S, Wp, out);
}

// Round 8
// 102.158 us; speedup vs baseline: 1.5763x; 1.1463x over previous
//
#include <hip/hip_runtime.h>
#include <math.h>

// Problem constants (from reference)
#define MM 129      // mesh points per axis (odd)
#define KP 132      // padded K dim
#define NP 512      // points per batch
#define NB 4        // batches
#define NPC 16      // p-chunks for the two-stage S reduction
#define PCHUNK (NP / NPC)

static constexpr double D_PI  = 3.14159265358979323846;
static constexpr double D_L   = 2.0 * D_PI;
static constexpr double D_TAU = 12.0 / ((double)MM * (double)MM);
static constexpr double D_INV4TAU = 1.0 / (4.0 * D_TAU);
// scale/M^2 = 1/(8*pi^2*M^4) folded into W tables
static constexpr double D_F = 1.0 / (8.0 * D_PI * D_PI * (double)MM * (double)MM * (double)MM * (double)MM);

__device__ __forceinline__ void cmac(float2& acc, float2 a, float2 b) {
    acc.x = fmaf(a.x, b.x, fmaf(-a.y, b.y, acc.x));
    acc.y = fmaf(a.x, b.y, fmaf( a.y, b.x, acc.y));
}

// ---------------------------------------------------------------------------
// Kernel 1: per-point Gaussian sampling + DFT for k = 64..127 (Hermitian:
// A[64-j] = conj(A[64+j])); k=128 via block reduce, k=0 = conj(k=128).
// Twiddles via per-thread register rotation (thread owns one kk -> one
// 1-sincos + 129 unit-modulus complex mults; throughput-bound, no table,
// no k_setup dependency). 2 points/block, 1024 blocks x 128 threads.
// ---------------------------------------------------------------------------
#define PPB 2
__global__ __launch_bounds__(128) void k_dft(const float* __restrict__ x,
                                             float2* __restrict__ A,
                                             float2* __restrict__ B) {
    const int p0  = blockIdx.x * PPB;    // global point index (b*512+p)
    const int tid = threadIdx.x;

    __shared__ float4 sG[MM];            // (ga_p0, gb_p0, ga_p1, gb_p1)
    __shared__ float red[2][8];

    const float inv4tau = (float)D_INV4TAU;
    const float Lf      = (float)D_L;
    for (int idx = tid; idx < MM * PPB; idx += 128) {
        int pt = idx & 1, a = idx >> 1;
        float x0 = x[(p0 + pt) * 2 + 0];
        float x1 = x[(p0 + pt) * 2 + 1];
        float u  = (float)a * (float)(D_L / MM);
        float d0 = x0 - u, d1 = x1 - u;
        float ga = expf(-d0 * d0 * inv4tau)
                 + expf(-(d0 - Lf) * (d0 - Lf) * inv4tau)
                 + expf(-(d0 + Lf) * (d0 + Lf) * inv4tau);
        float gb = expf(-d1 * d1 * inv4tau)
                 + expf(-(d1 - Lf) * (d1 - Lf) * inv4tau)
                 + expf(-(d1 + Lf) * (d1 + Lf) * inv4tau);
        ((float2*)&sG[a])[pt] = make_float2(ga, gb);
    }
    __syncthreads();

    const int pt = tid & 1;
    const int j  = tid >> 1;             // 0..63 -> k = 64+j, kc = j
    const int kk = 64 + j;
    const float nf = (float)(-2.0 * D_PI / MM);

    float sw, cw;
    __sincosf(nf * (float)j, &sw, &cw);  // w = exp(-2pi*i*j/M)
    float tx = 1.f, ty = 0.f;            // t(a) = w^a

    float Ar = 0.f, Ai = 0.f, Br = 0.f, Bi = 0.f;
    #pragma unroll 4
    for (int a = 0; a < MM; ++a) {
        float2 g = ((const float2*)&sG[a])[pt];        // 2 distinct addrs/wave
        Ar = fmaf(g.x, tx, Ar); Ai = fmaf(g.x, ty, Ai);
        Br = fmaf(g.y, tx, Br); Bi = fmaf(g.y, ty, Bi);
        float nx = fmaf(tx, cw, -(ty * sw));           // t *= w
        float ny = fmaf(tx, sw,   ty * cw);
        tx = nx; ty = ny;
    }

    {
        const size_t base = (size_t)(p0 + pt) * KP;
        A[base + kk] = make_float2(Ar, Ai);
        B[base + kk] = make_float2(Br, Bi);
        if (j > 0) {                                    // Hermitian mirror
            A[base + 64 - j] = make_float2(Ar, -Ai);
            B[base + 64 - j] = make_float2(Br, -Bi);
        }
    }

    // ----- k = 128 (kc=64): reduce over a across the block; k=0 = conj -----
    const int lane = tid & 63, wv = tid >> 6;
    float2 t1, t128;
    {   // t1 = exp(-2pi*i*64*a/M) at a = tid; exact integer phase reduction
        int ph = (64 * tid) % MM;
        __sincosf(nf * (float)ph, &t1.y, &t1.x);
        __sincosf(nf * 65.f, &t128.y, &t128.x);   // (64*128) % 129 = 65
    }
    float4 gt   = sG[tid];
    float4 g128 = sG[128];
    #pragma unroll
    for (int p = 0; p < PPB; ++p) {
        float ga = p ? gt.z : gt.x;
        float gb = p ? gt.w : gt.y;
        float ar = ga * t1.x, ai = ga * t1.y;
        float br = gb * t1.x, bi = gb * t1.y;
        if (tid == 0) {   // a = 128 term
            float ga8 = p ? g128.z : g128.x;
            float gb8 = p ? g128.w : g128.y;
            ar = fmaf(ga8, t128.x, ar); ai = fmaf(ga8, t128.y, ai);
            br = fmaf(gb8, t128.x, br); bi = fmaf(gb8, t128.y, bi);
        }
        #pragma unroll
        for (int o = 32; o > 0; o >>= 1) {
            ar += __shfl_down(ar, o, 64); ai += __shfl_down(ai, o, 64);
            br += __shfl_down(br, o, 64); bi += __shfl_down(bi, o, 64);
        }
        if (lane == 0) {
            red[wv][p * 4 + 0] = ar; red[wv][p * 4 + 1] = ai;
            red[wv][p * 4 + 2] = br; red[wv][p * 4 + 3] = bi;
        }
    }
    __syncthreads();
    if (tid < 4) {
        int p = tid >> 1, isB = tid & 1;
        float re = red[0][p * 4 + isB * 2 + 0] + red[1][p * 4 + isB * 2 + 0];
        float im = red[0][p * 4 + isB * 2 + 1] + red[1][p * 4 + isB * 2 + 1];
        float2* dst = isB ? B : A;
        const size_t base = (size_t)(p0 + p) * KP;
        dst[base + 128] = make_float2(re, im);
        dst[base + 0]   = make_float2(re, -im);
    }
}

// ---------------------------------------------------------------------------
// Kernel 2a: stage-1 of S: partial outer products, NO atomics.
// P[b][pc][m(0..67)][n] = sum_{p in chunk pc} A[b,p,m]*B[b,p,n]
// Grid: (17 m-tiles, 16 p-chunks, 4 batches) = 1088 blocks, 128 threads.
// ---------------------------------------------------------------------------
__global__ __launch_bounds__(128) void k_s1(const float2* __restrict__ A,
                                            const float2* __restrict__ B,
                                            float2* __restrict__ P) {
    const int b   = blockIdx.z;
    const int pc  = blockIdx.y;
    const int p0  = pc * PCHUNK;
    const int m0  = blockIdx.x * 4;       // 0..64
    const int tid = threadIdx.x;

    const float2* __restrict__ Ab = A + (size_t)b * NP * KP;
    const float2* __restrict__ Bb = B + (size_t)b * NP * KP;

    float2 acc[4];
    #pragma unroll
    for (int i = 0; i < 4; ++i) acc[i] = make_float2(0.f, 0.f);
    float2 acc2 = make_float2(0.f, 0.f);   // P[m0+lane][128], lanes 0..3

    float2 v[4], am[4][4], as[4], bu[4];
    #pragma unroll
    for (int i = 0; i < 4; ++i) {
        const size_t r = (size_t)(p0 + i) * KP;
        v[i]  = Bb[r + tid];
        bu[i] = Bb[r + 128];                 // wave-uniform
        as[i] = Ab[r + m0 + (tid & 3)];      // per-lane A for the n=128 path
        #pragma unroll
        for (int j = 0; j < 4; ++j) am[i][j] = Ab[r + m0 + j];   // wave-uniform
    }

    for (int pg = 0; pg < PCHUNK; pg += 4) {
        float2 nv[4], nam[4][4], nas[4], nbu[4];
        const bool more = (pg + 4 < PCHUNK);
        if (more) {
            #pragma unroll
            for (int i = 0; i < 4; ++i) {
                const size_t r = (size_t)(p0 + pg + 4 + i) * KP;
                nv[i]  = Bb[r + tid];
                nbu[i] = Bb[r + 128];
                nas[i] = Ab[r + m0 + (tid & 3)];
                #pragma unroll
                for (int j = 0; j < 4; ++j) nam[i][j] = Ab[r + m0 + j];
            }
        }
        #pragma unroll
        for (int i = 0; i < 4; ++i) {
            cmac(acc[0], am[i][0], v[i]);
            cmac(acc[1], am[i][1], v[i]);
            cmac(acc[2], am[i][2], v[i]);
            cmac(acc[3], am[i][3], v[i]);
        }
        if (tid < 4) {
            #pragma unroll
            for (int i = 0; i < 4; ++i) cmac(acc2, as[i], bu[i]);
        }
        if (more) {
            #pragma unroll
            for (int i = 0; i < 4; ++i) {
                v[i] = nv[i]; bu[i] = nbu[i]; as[i] = nas[i];
                #pragma unroll
                for (int j = 0; j < 4; ++j) am[i][j] = nam[i][j];
            }
        }
    }

    float2* Pb = P + ((size_t)(b * NPC + pc) * 68) * KP;
    #pragma unroll
    for (int i = 0; i < 4; ++i)
        Pb[(size_t)(m0 + i) * KP + tid] = acc[i];      // coalesced store
    if (tid < 4)
        Pb[(size_t)(m0 + tid) * KP + 128] = acc2;
}

// ---------------------------------------------------------------------------
// Kernel 2b (fused): S[b][m][n] = sum_pc P[b][pc][m][n]; also builds the W
// table (rows 0..64) and zeroes out — both needed only by k_final, which
// runs after this kernel. One dispatch fewer in the serial chain.
// ---------------------------------------------------------------------------
#define OUT_FLOATS (NB * NP * 2)
__global__ __launch_bounds__(256) void k_s2(const float2* __restrict__ P,
                                            float2* __restrict__ S,
                                            const float* __restrict__ s0p,
                                            const float* __restrict__ s1p,
                                            const float* __restrict__ a0p,
                                            const float* __restrict__ a1p,
                                            float2* __restrict__ Wp,
                                            float* __restrict__ out) {
    const int idx = blockIdx.x * 256 + threadIdx.x;

    if (idx < OUT_FLOATS) out[idx] = 0.f;

    if (idx < 65 * KP) {                  // W rows m = 0..64
        int m = idx / KP, n = idx - (idx / KP) * KP;
        float w0 = 0.f, w1 = 0.f;
        if (n < MM) {
            float kx = (float)(m - 64), ky = (float)(n - 64);
            float k2   = kx * kx + ky * ky;
            float dec  = (float)(D_PI / D_TAU) * expf(k2 * (float)D_TAU);
            float base = dec * dec * (float)(4.0 * D_PI * D_F);
            float s0 = s0p[0], s1 = s1p[0];   // mu0 = mu1 = 1
            w0 = a0p[0] * base / (k2 + s0 * s0);
            w1 = a1p[0] * base / (k2 + s1 * s1);
        }
        Wp[idx] = make_float2(w0, w1);
    }

    if (idx < NB * 68 * KP) {
        const int b   = idx / (68 * KP);
        const int rem = idx - b * (68 * KP);
        const int m   = rem / KP;
        const int n   = rem - m * KP;
        if (n <= 128) {                   // cols 129..131 never written/read
            const float2* __restrict__ Pb =
                P + ((size_t)b * NPC * 68) * KP + (size_t)m * KP + n;
            float re = 0.f, im = 0.f;
            #pragma unroll
            for (int pc = 0; pc < NPC; ++pc) {
                float2 vv = Pb[(size_t)pc * 68 * KP];
                re += vv.x; im += vv.y;
            }
            S[(size_t)b * KP * KP + (size_t)m * KP + n] = make_float2(re, im);
        }
    }
}

// ---------------------------------------------------------------------------
// Kernel 3: per point p (8 per block), both channels. Mirror symmetry:
//   full sum = 2*sum_{m<64, all n} + 2*sum_{m=64, n<64} + (m=64,n=64).
// Grid: (64 point-groups, 8 m-chunks of 8 rows, 4 batches) = 2048 blocks.
// ---------------------------------------------------------------------------
__global__ __launch_bounds__(128) void k_final(const float2* __restrict__ A,
                                               const float2* __restrict__ B,
                                               const float2* __restrict__ S,
                                               const float2* __restrict__ Wp,
                                               float* __restrict__ out) {
    const int b      = blockIdx.z;
    const int mc     = blockIdx.y;
    const int mstart = mc * 8;           // rows mstart..mstart+7 (<= 63)
    const int p0     = blockIdx.x * 8;
    const int tid    = threadIdx.x;

    __shared__ float2 sA[8][65];         // k = 0..64 (only m<=64 read)
    __shared__ float2 sB[8][KP];         // k = 0..128 used
    for (int idx = tid; idx < 8 * 65; idx += 128) {
        int pi = idx / 65, k = idx - pi * 65;
        sA[pi][k] = A[(size_t)(b * NP + p0 + pi) * KP + k];
    }
    for (int idx = tid; idx < 8 * 129; idx += 128) {
        int pi = idx / 129, k = idx - pi * 129;
        sB[pi][k] = B[(size_t)(b * NP + p0 + pi) * KP + k];
    }
    __syncthreads();

    float2 bb[8];
    #pragma unroll
    for (int pi = 0; pi < 8; ++pi) bb[pi] = sB[pi][tid];

    float e0[8], e1[8];
    #pragma unroll
    for (int i = 0; i < 8; ++i) { e0[i] = 0.f; e1[i] = 0.f; }

    const float2* __restrict__ Sb = S + (size_t)b * KP * KP;
    float2 s = Sb[(size_t)mstart * KP + tid];
    float2 w = Wp[(size_t)mstart * KP + tid];
    #pragma unroll
    for (int mi = 0; mi < 8; ++mi) {
        const int m = mstart + mi;
        float2 sn = s, wn = w;
        if (mi < 7) {
            sn = Sb[(size_t)(m + 1) * KP + tid];
            wn = Wp[(size_t)(m + 1) * KP + tid];
        }
        #pragma unroll
        for (int pi = 0; pi < 8; ++pi) {
            float2 a  = sA[pi][m];            // broadcast
            float2 bv = bb[pi];
            float abr = a.x * bv.x - a.y * bv.y;
            float abi = a.x * bv.y + a.y * bv.x;
            float d   = fmaf(s.x, abr, s.y * abi) - fmaf(abr, abr, abi * abi);
            e0[pi] = fmaf(w.x, d, e0[pi]);
            e1[pi] = fmaf(w.y, d, e1[pi]);
        }
        s = sn; w = wn;
    }
    // n = 128 column for this chunk's rows (all m <= 63, weight 2 via fold)
    if (tid < 8) {
        const int m = mstart + tid;
        float2 s8 = Sb[(size_t)m * KP + 128];
        float2 w8 = Wp[(size_t)m * KP + 128];
        #pragma unroll
        for (int pi = 0; pi < 8; ++pi) {
            float2 a  = sA[pi][m];
            float2 bv = sB[pi][128];
            float abr = a.x * bv.x - a.y * bv.y;
            float abi = a.x * bv.y + a.y * bv.x;
            float d   = fmaf(s8.x, abr, s8.y * abi) - fmaf(abr, abr, abi * abi);
            e0[pi] = fmaf(w8.x, d, e0[pi]);
            e1[pi] = fmaf(w8.y, d, e1[pi]);
        }
    }
    // fold the mirror weight (x2) for all m < 64 contributions
    #pragma unroll
    for (int i = 0; i < 8; ++i) { e0[i] *= 2.f; e1[i] *= 2.f; }

    // mc==7: the self-mirror row m=64: n<64 weight 2, n=64 weight 1, n>64 none
    if (mc == 7) {
        float wt = (tid < 64) ? 2.f : ((tid == 64) ? 1.f : 0.f);
        float2 s64 = Sb[(size_t)64 * KP + tid];
        float2 w64 = Wp[(size_t)64 * KP + tid];
        w64.x *= wt; w64.y *= wt;
        #pragma unroll
        for (int pi = 0; pi < 8; ++pi) {
            float2 a  = sA[pi][64];
            float2 bv = bb[pi];
            float abr = a.x * bv.x - a.y * bv.y;
            float abi = a.x * bv.y + a.y * bv.x;
            float d   = fmaf(s64.x, abr, s64.y * abi) - fmaf(abr, abr, abi * abi);
            e0[pi] = fmaf(w64.x, d, e0[pi]);
            e1[pi] = fmaf(w64.y, d, e1[pi]);
        }
    }

    // reduce 128 threads -> 16 partials (8 points x 2 channels), atomic to out
    const int lane = tid & 63, wv = tid >> 6;
    __shared__ float part[2][16];
    #pragma unroll
    for (int pi = 0; pi < 8; ++pi) {
        float r0 = e0[pi], r1 = e1[pi];
        #pragma unroll
        for (int o = 32; o > 0; o >>= 1) {
            r0 += __shfl_down(r0, o, 64);
            r1 += __shfl_down(r1, o, 64);
        }
        if (lane == 0) { part[wv][pi * 2 + 0] = r0; part[wv][pi * 2 + 1] = r1; }
    }
    __syncthreads();
    if (tid < 16) {
        float r = part[0][tid] + part[1][tid];
        int pi = tid >> 1, c = tid & 1;
        atomicAdd(&out[((size_t)(b * NP + p0 + pi)) * 2 + c], r);
    }
}

// ---------------------------------------------------------------------------
extern "C" void kernel_launch(void* const* d_in, const int* in_sizes, int n_in,
                              void* d_out, int out_size, void* d_ws, size_t ws_size,
                              hipStream_t stream) {
    const float* x      = (const float*)d_in[0];
    const float* shift0 = (const float*)d_in[1];
    const float* shift1 = (const float*)d_in[2];
    const float* amp0   = (const float*)d_in[3];
    const float* amp1   = (const float*)d_in[4];
    float* out = (float*)d_out;

    // workspace layout (float2-aligned)
    float2* A  = (float2*)d_ws;                 // [NB][NP][KP]
    float2* Bv = A + (size_t)NB * NP * KP;      // [NB][NP][KP]
    float2* S  = Bv + (size_t)NB * NP * KP;     // [NB][KP][KP]
    float2* Wp = S + (size_t)NB * KP * KP;      // [65*KP] packed (w0,w1)
    float2* P  = Wp + (size_t)65 * KP;          // [NB*NPC][68][KP] partials (~4.6 MB)

    k_dft<<<(NB * NP) / PPB, 128, 0, stream>>>(x, A, Bv);
    k_s1<<<dim3(17, NPC, NB), 128, 0, stream>>>(A, Bv, P);
    k_s2<<<(NB * 68 * KP + 255) / 256, 256, 0, stream>>>(P, S, shift0, shift1,
                                                         amp0, amp1, Wp, out);
    k_final<<<dim3(NP / 8, 8, NB), 128, 0, stream>>>(A, Bv, S, Wp, out);
}

// Round 9
// 100.331 us; speedup vs baseline: 1.6050x; 1.0182x over previous
//
#include <hip/hip_runtime.h>
#include <math.h>

// Problem constants (from reference)
#define MM 129      // mesh points per axis (odd)
#define KP 132      // padded K dim
#define NP 512      // points per batch
#define NB 4        // batches
#define NPC 16      // p-chunks for the two-stage S reduction
#define PCHUNK (NP / NPC)

static constexpr double D_PI  = 3.14159265358979323846;
static constexpr double D_L   = 2.0 * D_PI;
static constexpr double D_TAU = 12.0 / ((double)MM * (double)MM);
static constexpr double D_INV4TAU = 1.0 / (4.0 * D_TAU);
// scale/M^2 = 1/(8*pi^2*M^4) folded into W tables
static constexpr double D_F = 1.0 / (8.0 * D_PI * D_PI * (double)MM * (double)MM * (double)MM * (double)MM);

__device__ __forceinline__ void cmac(float2& acc, float2 a, float2 b) {
    acc.x = fmaf(a.x, b.x, fmaf(-a.y, b.y, acc.x));
    acc.y = fmaf(a.x, b.y, fmaf( a.y, b.x, acc.y));
}

// ---------------------------------------------------------------------------
// Kernel 1: per-point Gaussian sampling + DFT for k = 64..127 (Hermitian:
// A[64-j] = conj(A[64+j])); k=128 via block reduce, k=0 = conj(k=128).
// Twiddles: per-thread register rotation, EXACT-RESYNCED every 16 steps from
// the integer-reduced phase (16c*j mod 129) — kills the 129-step drift that
// cost absmax 0.5 in R8 while keeping the no-table structure.
// 2 points/block, 1024 blocks x 128 threads.
// ---------------------------------------------------------------------------
#define PPB 2
__global__ __launch_bounds__(128) void k_dft(const float* __restrict__ x,
                                             float2* __restrict__ A,
                                             float2* __restrict__ B) {
    const int p0  = blockIdx.x * PPB;    // global point index (b*512+p)
    const int tid = threadIdx.x;

    __shared__ float4 sG[MM];            // (ga_p0, gb_p0, ga_p1, gb_p1)
    __shared__ float red[2][8];

    const float inv4tau = (float)D_INV4TAU;
    const float Lf      = (float)D_L;
    for (int idx = tid; idx < MM * PPB; idx += 128) {
        int pt = idx & 1, a = idx >> 1;
        float x0 = x[(p0 + pt) * 2 + 0];
        float x1 = x[(p0 + pt) * 2 + 1];
        float u  = (float)a * (float)(D_L / MM);
        float d0 = x0 - u, d1 = x1 - u;
        float ga = __expf(-d0 * d0 * inv4tau)
                 + __expf(-(d0 - Lf) * (d0 - Lf) * inv4tau)
                 + __expf(-(d0 + Lf) * (d0 + Lf) * inv4tau);
        float gb = __expf(-d1 * d1 * inv4tau)
                 + __expf(-(d1 - Lf) * (d1 - Lf) * inv4tau)
                 + __expf(-(d1 + Lf) * (d1 + Lf) * inv4tau);
        ((float2*)&sG[a])[pt] = make_float2(ga, gb);
    }
    __syncthreads();

    const int pt = tid & 1;
    const int j  = tid >> 1;             // 0..63 -> k = 64+j, kc = j
    const int kk = 64 + j;
    const float nf = (float)(-2.0 * D_PI / MM);

    float sw, cw;
    __sincosf(nf * (float)j, &sw, &cw);  // w = exp(-2pi*i*j/M)
    const int step16 = (j * 16) % MM;
    int idx = 0;                         // (j*a) mod M at chunk start

    float Ar = 0.f, Ai = 0.f, Br = 0.f, Bi = 0.f;
    for (int c = 0; c < 128; c += 16) {
        float st, ct;
        __sincosf(nf * (float)idx, &st, &ct);          // exact resync
        float tx = ct, ty = st;
        #pragma unroll
        for (int q = 0; q < 16; ++q) {
            float2 g = ((const float2*)&sG[c + q])[pt];
            Ar = fmaf(g.x, tx, Ar); Ai = fmaf(g.x, ty, Ai);
            Br = fmaf(g.y, tx, Br); Bi = fmaf(g.y, ty, Bi);
            float nx = fmaf(tx, cw, -(ty * sw));       // t *= w
            float ny = fmaf(tx, sw,   ty * cw);
            tx = nx; ty = ny;
        }
        idx += step16; if (idx >= MM) idx -= MM;
    }
    {   // a = 128 tail (exact phase)
        float st, ct;
        __sincosf(nf * (float)idx, &st, &ct);
        float2 g = ((const float2*)&sG[128])[pt];
        Ar = fmaf(g.x, ct, Ar); Ai = fmaf(g.x, st, Ai);
        Br = fmaf(g.y, ct, Br); Bi = fmaf(g.y, st, Bi);
    }

    {
        const size_t base = (size_t)(p0 + pt) * KP;
        A[base + kk] = make_float2(Ar, Ai);
        B[base + kk] = make_float2(Br, Bi);
        if (j > 0) {                                    // Hermitian mirror
            A[base + 64 - j] = make_float2(Ar, -Ai);
            B[base + 64 - j] = make_float2(Br, -Bi);
        }
    }

    // ----- k = 128 (kc=64): reduce over a across the block; k=0 = conj -----
    const int lane = tid & 63, wv = tid >> 6;
    float2 t1, t128;
    {   // t1 = exp(-2pi*i*64*a/M) at a = tid; exact integer phase reduction
        int ph = (64 * tid) % MM;
        __sincosf(nf * (float)ph, &t1.y, &t1.x);
        __sincosf(nf * 65.f, &t128.y, &t128.x);   // (64*128) % 129 = 65
    }
    float4 gt   = sG[tid];
    float4 g128 = sG[128];
    #pragma unroll
    for (int p = 0; p < PPB; ++p) {
        float ga = p ? gt.z : gt.x;
        float gb = p ? gt.w : gt.y;
        float ar = ga * t1.x, ai = ga * t1.y;
        float br = gb * t1.x, bi = gb * t1.y;
        if (tid == 0) {   // a = 128 term
            float ga8 = p ? g128.z : g128.x;
            float gb8 = p ? g128.w : g128.y;
            ar = fmaf(ga8, t128.x, ar); ai = fmaf(ga8, t128.y, ai);
            br = fmaf(gb8, t128.x, br); bi = fmaf(gb8, t128.y, bi);
        }
        #pragma unroll
        for (int o = 32; o > 0; o >>= 1) {
            ar += __shfl_down(ar, o, 64); ai += __shfl_down(ai, o, 64);
            br += __shfl_down(br, o, 64); bi += __shfl_down(bi, o, 64);
        }
        if (lane == 0) {
            red[wv][p * 4 + 0] = ar; red[wv][p * 4 + 1] = ai;
            red[wv][p * 4 + 2] = br; red[wv][p * 4 + 3] = bi;
        }
    }
    __syncthreads();
    if (tid < 4) {
        int p = tid >> 1, isB = tid & 1;
        float re = red[0][p * 4 + isB * 2 + 0] + red[1][p * 4 + isB * 2 + 0];
        float im = red[0][p * 4 + isB * 2 + 1] + red[1][p * 4 + isB * 2 + 1];
        float2* dst = isB ? B : A;
        const size_t base = (size_t)(p0 + p) * KP;
        dst[base + 128] = make_float2(re, im);
        dst[base + 0]   = make_float2(re, -im);
    }
}

// ---------------------------------------------------------------------------
// Kernel 2a: stage-1 of S: partial outer products, NO atomics.
// P[b][pc][m(0..67)][n] = sum_{p in chunk pc} A[b,p,m]*B[b,p,n]
// Grid: (17 m-tiles, 16 p-chunks, 4 batches) = 1088 blocks, 128 threads.
// ---------------------------------------------------------------------------
__global__ __launch_bounds__(128) void k_s1(const float2* __restrict__ A,
                                            const float2* __restrict__ B,
                                            float2* __restrict__ P) {
    const int b   = blockIdx.z;
    const int pc  = blockIdx.y;
    const int p0  = pc * PCHUNK;
    const int m0  = blockIdx.x * 4;       // 0..64
    const int tid = threadIdx.x;

    const float2* __restrict__ Ab = A + (size_t)b * NP * KP;
    const float2* __restrict__ Bb = B + (size_t)b * NP * KP;

    float2 acc[4];
    #pragma unroll
    for (int i = 0; i < 4; ++i) acc[i] = make_float2(0.f, 0.f);
    float2 acc2 = make_float2(0.f, 0.f);   // P[m0+lane][128], lanes 0..3

    float2 v[4], am[4][4], as[4], bu[4];
    #pragma unroll
    for (int i = 0; i < 4; ++i) {
        const size_t r = (size_t)(p0 + i) * KP;
        v[i]  = Bb[r + tid];
        bu[i] = Bb[r + 128];                 // wave-uniform
        as[i] = Ab[r + m0 + (tid & 3)];      // per-lane A for the n=128 path
        #pragma unroll
        for (int j = 0; j < 4; ++j) am[i][j] = Ab[r + m0 + j];   // wave-uniform
    }

    for (int pg = 0; pg < PCHUNK; pg += 4) {
        float2 nv[4], nam[4][4], nas[4], nbu[4];
        const bool more = (pg + 4 < PCHUNK);
        if (more) {
            #pragma unroll
            for (int i = 0; i < 4; ++i) {
                const size_t r = (size_t)(p0 + pg + 4 + i) * KP;
                nv[i]  = Bb[r + tid];
                nbu[i] = Bb[r + 128];
                nas[i] = Ab[r + m0 + (tid & 3)];
                #pragma unroll
                for (int j = 0; j < 4; ++j) nam[i][j] = Ab[r + m0 + j];
            }
        }
        #pragma unroll
        for (int i = 0; i < 4; ++i) {
            cmac(acc[0], am[i][0], v[i]);
            cmac(acc[1], am[i][1], v[i]);
            cmac(acc[2], am[i][2], v[i]);
            cmac(acc[3], am[i][3], v[i]);
        }
        if (tid < 4) {
            #pragma unroll
            for (int i = 0; i < 4; ++i) cmac(acc2, as[i], bu[i]);
        }
        if (more) {
            #pragma unroll
            for (int i = 0; i < 4; ++i) {
                v[i] = nv[i]; bu[i] = nbu[i]; as[i] = nas[i];
                #pragma unroll
                for (int j = 0; j < 4; ++j) am[i][j] = nam[i][j];
            }
        }
    }

    float2* Pb = P + ((size_t)(b * NPC + pc) * 68) * KP;
    #pragma unroll
    for (int i = 0; i < 4; ++i)
        Pb[(size_t)(m0 + i) * KP + tid] = acc[i];      // coalesced store
    if (tid < 4)
        Pb[(size_t)(m0 + tid) * KP + 128] = acc2;
}

// ---------------------------------------------------------------------------
// Kernel 2b (fused): S[b][m][n] = sum_pc P[b][pc][m][n]; also builds the W
// table (rows 0..64) and zeroes out — both needed only by k_final.
// ---------------------------------------------------------------------------
#define OUT_FLOATS (NB * NP * 2)
__global__ __launch_bounds__(256) void k_s2(const float2* __restrict__ P,
                                            float2* __restrict__ S,
                                            const float* __restrict__ s0p,
                                            const float* __restrict__ s1p,
                                            const float* __restrict__ a0p,
                                            const float* __restrict__ a1p,
                                            float2* __restrict__ Wp,
                                            float* __restrict__ out) {
    const int idx = blockIdx.x * 256 + threadIdx.x;

    if (idx < OUT_FLOATS) out[idx] = 0.f;

    if (idx < 65 * KP) {                  // W rows m = 0..64
        int m = idx / KP, n = idx - (idx / KP) * KP;
        float w0 = 0.f, w1 = 0.f;
        if (n < MM) {
            float kx = (float)(m - 64), ky = (float)(n - 64);
            float k2   = kx * kx + ky * ky;
            float dec  = (float)(D_PI / D_TAU) * expf(k2 * (float)D_TAU);
            float base = dec * dec * (float)(4.0 * D_PI * D_F);
            float s0 = s0p[0], s1 = s1p[0];   // mu0 = mu1 = 1
            w0 = a0p[0] * base / (k2 + s0 * s0);
            w1 = a1p[0] * base / (k2 + s1 * s1);
        }
        Wp[idx] = make_float2(w0, w1);
    }

    if (idx < NB * 68 * KP) {
        const int b   = idx / (68 * KP);
        const int rem = idx - b * (68 * KP);
        const int m   = rem / KP;
        const int n   = rem - m * KP;
        if (n <= 128) {                   // cols 129..131 never written/read
            const float2* __restrict__ Pb =
                P + ((size_t)b * NPC * 68) * KP + (size_t)m * KP + n;
            float re = 0.f, im = 0.f;
            #pragma unroll
            for (int pc = 0; pc < NPC; ++pc) {
                float2 vv = Pb[(size_t)pc * 68 * KP];
                re += vv.x; im += vv.y;
            }
            S[(size_t)b * KP * KP + (size_t)m * KP + n] = make_float2(re, im);
        }
    }
}

// ---------------------------------------------------------------------------
// Kernel 3: per point p (8 per block), both channels. Mirror symmetry:
//   full sum = 2*sum_{m<64, all n} + 2*sum_{m=64, n<64} + (m=64,n=64).
// Grid: (64 point-groups, 8 m-chunks of 8 rows, 4 batches) = 2048 blocks.
// ---------------------------------------------------------------------------
__global__ __launch_bounds__(128) void k_final(const float2* __restrict__ A,
                                               const float2* __restrict__ B,
                                               const float2* __restrict__ S,
                                               const float2* __restrict__ Wp,
                                               float* __restrict__ out) {
    const int b      = blockIdx.z;
    const int mc     = blockIdx.y;
    const int mstart = mc * 8;           // rows mstart..mstart+7 (<= 63)
    const int p0     = blockIdx.x * 8;
    const int tid    = threadIdx.x;

    __shared__ float2 sA[8][65];         // k = 0..64 (only m<=64 read)
    __shared__ float2 sB[8][KP];         // k = 0..128 used
    for (int idx = tid; idx < 8 * 65; idx += 128) {
        int pi = idx / 65, k = idx - pi * 65;
        sA[pi][k] = A[(size_t)(b * NP + p0 + pi) * KP + k];
    }
    for (int idx = tid; idx < 8 * 129; idx += 128) {
        int pi = idx / 129, k = idx - pi * 129;
        sB[pi][k] = B[(size_t)(b * NP + p0 + pi) * KP + k];
    }
    __syncthreads();

    float2 bb[8];
    #pragma unroll
    for (int pi = 0; pi < 8; ++pi) bb[pi] = sB[pi][tid];

    float e0[8], e1[8];
    #pragma unroll
    for (int i = 0; i < 8; ++i) { e0[i] = 0.f; e1[i] = 0.f; }

    const float2* __restrict__ Sb = S + (size_t)b * KP * KP;
    float2 s = Sb[(size_t)mstart * KP + tid];
    float2 w = Wp[(size_t)mstart * KP + tid];
    #pragma unroll
    for (int mi = 0; mi < 8; ++mi) {
        const int m = mstart + mi;
        float2 sn = s, wn = w;
        if (mi < 7) {
            sn = Sb[(size_t)(m + 1) * KP + tid];
            wn = Wp[(size_t)(m + 1) * KP + tid];
        }
        #pragma unroll
        for (int pi = 0; pi < 8; ++pi) {
            float2 a  = sA[pi][m];            // broadcast
            float2 bv = bb[pi];
            float abr = a.x * bv.x - a.y * bv.y;
            float abi = a.x * bv.y + a.y * bv.x;
            float d   = fmaf(s.x, abr, s.y * abi) - fmaf(abr, abr, abi * abi);
            e0[pi] = fmaf(w.x, d, e0[pi]);
            e1[pi] = fmaf(w.y, d, e1[pi]);
        }
        s = sn; w = wn;
    }
    // n = 128 column for this chunk's rows (all m <= 63, weight 2 via fold)
    if (tid < 8) {
        const int m = mstart + tid;
        float2 s8 = Sb[(size_t)m * KP + 128];
        float2 w8 = Wp[(size_t)m * KP + 128];
        #pragma unroll
        for (int pi = 0; pi < 8; ++pi) {
            float2 a  = sA[pi][m];
            float2 bv = sB[pi][128];
            float abr = a.x * bv.x - a.y * bv.y;
            float abi = a.x * bv.y + a.y * bv.x;
            float d   = fmaf(s8.x, abr, s8.y * abi) - fmaf(abr, abr, abi * abi);
            e0[pi] = fmaf(w8.x, d, e0[pi]);
            e1[pi] = fmaf(w8.y, d, e1[pi]);
        }
    }
    // fold the mirror weight (x2) for all m < 64 contributions
    #pragma unroll
    for (int i = 0; i < 8; ++i) { e0[i] *= 2.f; e1[i] *= 2.f; }

    // mc==7: the self-mirror row m=64: n<64 weight 2, n=64 weight 1, n>64 none
    if (mc == 7) {
        float wt = (tid < 64) ? 2.f : ((tid == 64) ? 1.f : 0.f);
        float2 s64 = Sb[(size_t)64 * KP + tid];
        float2 w64 = Wp[(size_t)64 * KP + tid];
        w64.x *= wt; w64.y *= wt;
        #pragma unroll
        for (int pi = 0; pi < 8; ++pi) {
            float2 a  = sA[pi][64];
            float2 bv = bb[pi];
            float abr = a.x * bv.x - a.y * bv.y;
            float abi = a.x * bv.y + a.y * bv.x;
            float d   = fmaf(s64.x, abr, s64.y * abi) - fmaf(abr, abr, abi * abi);
            e0[pi] = fmaf(w64.x, d, e0[pi]);
            e1[pi] = fmaf(w64.y, d, e1[pi]);
        }
    }

    // reduce 128 threads -> 16 partials (8 points x 2 channels), atomic to out
    const int lane = tid & 63, wv = tid >> 6;
    __shared__ float part[2][16];
    #pragma unroll
    for (int pi = 0; pi < 8; ++pi) {
        float r0 = e0[pi], r1 = e1[pi];
        #pragma unroll
        for (int o = 32; o > 0; o >>= 1) {
            r0 += __shfl_down(r0, o, 64);
            r1 += __shfl_down(r1, o, 64);
        }
        if (lane == 0) { part[wv][pi * 2 + 0] = r0; part[wv][pi * 2 + 1] = r1; }
    }
    __syncthreads();
    if (tid < 16) {
        float r = part[0][tid] + part[1][tid];
        int pi = tid >> 1, c = tid & 1;
        atomicAdd(&out[((size_t)(b * NP + p0 + pi)) * 2 + c], r);
    }
}

// ---------------------------------------------------------------------------
extern "C" void kernel_launch(void* const* d_in, const int* in_sizes, int n_in,
                              void* d_out, int out_size, void* d_ws, size_t ws_size,
                              hipStream_t stream) {
    const float* x      = (const float*)d_in[0];
    const float* shift0 = (const float*)d_in[1];
    const float* shift1 = (const float*)d_in[2];
    const float* amp0   = (const float*)d_in[3];
    const float* amp1   = (const float*)d_in[4];
    float* out = (float*)d_out;

    // workspace layout (float2-aligned)
    float2* A  = (float2*)d_ws;                 // [NB][NP][KP]
    float2* Bv = A + (size_t)NB * NP * KP;      // [NB][NP][KP]
    float2* S  = Bv + (size_t)NB * NP * KP;     // [NB][KP][KP]
    float2* Wp = S + (size_t)NB * KP * KP;      // [65*KP] packed (w0,w1)
    float2* P  = Wp + (size_t)65 * KP;          // [NB*NPC][68][KP] partials (~4.6 MB)

    k_dft<<<(NB * NP) / PPB, 128, 0, stream>>>(x, A, Bv);
    k_s1<<<dim3(17, NPC, NB), 128, 0, stream>>>(A, Bv, P);
    k_s2<<<(NB * 68 * KP + 255) / 256, 256, 0, stream>>>(P, S, shift0, shift1,
                                                         amp0, amp1, Wp, out);
    k_final<<<dim3(NP / 8, 8, NB), 128, 0, stream>>>(A, Bv, S, Wp, out);
}